// Round 14
// baseline (499.345 us; speedup 1.0000x reference)
//
#include <hip/hip_runtime.h>
#include <hip/hip_fp16.h>
#include <math.h>

#define N_HID 256
#define N_HEADS 4
#define N_HC 1024
#define N_GRAPHS 64

typedef __attribute__((ext_vector_type(4))) float f32x4;
typedef _Float16 half8 __attribute__((ext_vector_type(8)));
typedef _Float16 half4 __attribute__((ext_vector_type(4)));

__device__ __forceinline__ void gl_lds16h(const __half* g, __half* l) {
    __builtin_amdgcn_global_load_lds(
        (const __attribute__((address_space(1))) unsigned int*)g,
        (__attribute__((address_space(3))) unsigned int*)l, 16, 0, 0);
}

// ---------------------------------------------------------------- CSR build
__global__ __launch_bounds__(256) void k_deg(const int* __restrict__ dst, int E,
                                             int* __restrict__ deg) {
    int e = blockIdx.x * 256 + threadIdx.x;
    if (e < E) atomicAdd(&deg[dst[e]], 1);
}

__global__ __launch_bounds__(1024) void k_scan(const int* __restrict__ deg,
                                               int* __restrict__ rowstart, int N) {
    __shared__ int part[1024];
    const int t = threadIdx.x;
    const int chunk = (N + 1023) / 1024;
    const int c0 = t * chunk;
    int s = 0;
    for (int i = 0; i < chunk; i++) {
        int idx = c0 + i;
        if (idx < N) s += deg[idx];
    }
    part[t] = s;
    __syncthreads();
    for (int off = 1; off < 1024; off <<= 1) {
        int v = (t >= off) ? part[t - off] : 0;
        __syncthreads();
        part[t] += v;
        __syncthreads();
    }
    int run = (t == 0) ? 0 : part[t - 1];
    if (t == 0) rowstart[0] = 0;
    for (int i = 0; i < chunk; i++) {
        int idx = c0 + i;
        if (idx < N) {
            run += deg[idx];
            rowstart[idx + 1] = run;
        }
    }
}

__global__ __launch_bounds__(256) void k_fill(const int* __restrict__ src,
                                              const int* __restrict__ dst, int E,
                                              const int* __restrict__ rowstart,
                                              int* __restrict__ cursor,
                                              int* __restrict__ col) {
    int e = blockIdx.x * 256 + threadIdx.x;
    if (e < E) {
        int d = dst[e];
        int p = atomicAdd(&cursor[d], 1);
        col[rowstart[d] + p] = src[e];
    }
}

// ---------------------------------------------------------------- tiled transpose fp32[K][N] -> fp16[N][K]
__global__ __launch_bounds__(256) void k_wtt(const float* __restrict__ W,
                                             __half* __restrict__ WT, int K, int N) {
    __shared__ float tile[32][33];
    const int k0 = blockIdx.y * 32, n0 = blockIdx.x * 32;
    const int tr = threadIdx.x >> 5, tc = threadIdx.x & 31;
#pragma unroll
    for (int rr = 0; rr < 4; rr++) {
        int k = k0 + tr + rr * 8;
        tile[tr + rr * 8][tc] = W[(size_t)k * N + n0 + tc];
    }
    __syncthreads();
#pragma unroll
    for (int rr = 0; rr < 4; rr++) {
        int n = n0 + tr + rr * 8;
        WT[(size_t)n * K + k0 + tc] = __float2half(tile[tc][tr + rr * 8]);
    }
}

// ---------------------------------------------------------------- va = W1_h @ att_h (layer 1, from W1T fp16)
__global__ __launch_bounds__(256) void k_makeva(const __half* __restrict__ W1T,
                                                const float* __restrict__ as1,
                                                const float* __restrict__ ad1,
                                                float* __restrict__ va) {
    __shared__ float satt[256];
    int b = blockIdx.x;       // 0..7
    int h = b & 3, isd = b >> 2;
    int k = threadIdx.x;      // 0..255
    const float* att = (isd ? ad1 : as1) + h * 256;
    satt[k] = att[k];
    __syncthreads();
    const __half* wr = W1T + (size_t)(h * 256) * 256 + k;
    float s = 0.f;
    for (int c = 0; c < 256; c++) s += __half2float(wr[(size_t)c * 256]) * satt[c];
    va[b * 256 + k] = s;
}

// ---------------------------------------------------------------- va2 = W2_h^T @ att2_h (layer 2, chunked + atomic)
__global__ __launch_bounds__(256) void k_makeva2(const __half* __restrict__ W2T,
                                                 const float* __restrict__ as2,
                                                 const float* __restrict__ ad2,
                                                 float* __restrict__ va2) {
    __shared__ float satt[32];
    int b = blockIdx.x;   // 0..7
    int h = b & 3;
    int jc = blockIdx.y;  // 0..7
    int t = threadIdx.x;
    const float* att = (b >= 4 ? ad2 : as2) + h * 256 + jc * 32;
    if (t < 32) satt[t] = att[t];
    __syncthreads();
    float s0 = 0.f, s1 = 0.f, s2 = 0.f, s3 = 0.f;
    const __half* base = W2T + (size_t)(h * 256 + jc * 32) * 1024 + t * 4;
    for (int j = 0; j < 32; j++) {
        half4 wv = *reinterpret_cast<const half4*>(base + (size_t)j * 1024);
        float a = satt[j];
        s0 += a * (float)wv[0]; s1 += a * (float)wv[1];
        s2 += a * (float)wv[2]; s3 += a * (float)wv[3];
    }
    float* o = va2 + b * 1024 + t * 4;
    atomicAdd(o + 0, s0); atomicAdd(o + 1, s1);
    atomicAdd(o + 2, s2); atomicAdd(o + 3, s3);
}

// ---------------------------------------------------------------- 2-phase dbuf fp16 MFMA GEMM (BK=32)
template <int EPI, int COSCHED>
__global__ __launch_bounds__(256) void k_gemm2p(
    const __half* __restrict__ A, const __half* __restrict__ BT,
    const float* __restrict__ bias, __half* __restrict__ C,
    int M, int NROW, int K, int lda, int ldc,
    int aoffz, int boffz, int coffz, int bofz) {
    __shared__ __half sA[2][128 * 32];
    __shared__ __half sB[2][128 * 32];
    int bm, bn;
    size_t coff = 0;
    if (COSCHED) {
        const int bid = blockIdx.x;
        const int xcd = bid & 7, j0 = bid >> 3;
        const int br = xcd + 8 * (j0 >> 3);
        const int bc = j0 & 7;
        if (br >= NROW) return;
        bm = br * 128; bn = bc * 128;
    } else {
        const int z = blockIdx.z;
        A += (size_t)z * aoffz;
        BT += (size_t)z * boffz;
        bias += z * bofz;
        coff = (size_t)z * coffz;
        bm = blockIdx.y * 128; bn = blockIdx.x * 128;
    }
    const int tid = threadIdx.x, lane = tid & 63, w = tid >> 6;
    const int wr = (w >> 1) * 64, wc = (w & 1) * 64;
    const bool isB = (w >= 2);
    const __half* gsrc = isB ? (BT + (size_t)bn * K) : (A + (size_t)bm * lda);
    const int gld = isB ? K : lda;
    const int rbase = (w & 1) * 64;
    const int lr = lane >> 2, lsl = lane & 3;
    const int g = lane >> 4, fr = lane & 15;
    const int nt = K >> 5;

    f32x4 acc[4][4] = {};

    auto STAGE = [&](int b, int t) {
        __half* sbuf = (isB ? sB[b] : sA[b]);
        const int k0 = t << 5;
#pragma unroll
        for (int c2 = 0; c2 < 4; c2++) {
            int row = rbase + c2 * 16 + lr;
            int slg = lsl ^ ((row >> 1) & 3);
            gl_lds16h(gsrc + (size_t)row * gld + k0 + slg * 8,
                      sbuf + (rbase + c2 * 16) * 32);
        }
    };

    STAGE(0, 0);
    int cur = 0;
    for (int t = 0; t < nt; ++t) {
        if (t + 1 < nt) {
            STAGE(cur ^ 1, t + 1);
            asm volatile("s_waitcnt vmcnt(4)" ::: "memory");
        } else {
            asm volatile("s_waitcnt vmcnt(0)" ::: "memory");
        }
        asm volatile("s_barrier" ::: "memory");
        half8 af[4], bf[4];
#pragma unroll
        for (int i = 0; i < 4; i++) {
            int Ra = wr + i * 16 + fr;
            af[i] = *reinterpret_cast<const half8*>(
                &sA[cur][Ra * 32 + ((g ^ ((Ra >> 1) & 3)) << 3)]);
            int Rb = wc + i * 16 + fr;
            bf[i] = *reinterpret_cast<const half8*>(
                &sB[cur][Rb * 32 + ((g ^ ((Rb >> 1) & 3)) << 3)]);
        }
#pragma unroll
        for (int i = 0; i < 4; i++)
#pragma unroll
            for (int j = 0; j < 4; j++)
                acc[i][j] = __builtin_amdgcn_mfma_f32_16x16x32_f16(af[i], bf[j], acc[i][j], 0, 0, 0);
        asm volatile("s_barrier" ::: "memory");
        cur ^= 1;
    }
    const int crow0 = (lane >> 4) * 4, ccol = lane & 15;
#pragma unroll
    for (int i = 0; i < 4; i++)
#pragma unroll
        for (int j = 0; j < 4; j++) {
            int cc = bn + wc + j * 16 + ccol;
            float bv = (EPI == 2) ? bias[cc] : 0.f;
#pragma unroll
            for (int r = 0; r < 4; r++) {
                int row = bm + wr + i * 16 + crow0 + r;
                if (row < M) {
                    float v = acc[i][j][r];
                    if (EPI == 2) { v += bv; v = v > 0.f ? v : (__expf(v) - 1.f); }
                    C[(size_t)row * ldc + coff + cc] = __float2half(v);
                }
            }
        }
}

// ---------------------------------------------------------------- fp32-A MFMA GEMM (fused convert), bias+relu
__global__ __launch_bounds__(256) void k_gemm_x(
    const float* __restrict__ A, const __half* __restrict__ BT,
    const float* __restrict__ bias, __half* __restrict__ C,
    int M, int NROW, int K, int lda) {
    __shared__ __half sA[128 * 32];
    __shared__ __half sB[128 * 32];
    const int bid = blockIdx.x;
    const int xcd = bid & 7, j0 = bid >> 3;
    const int br = xcd + 8 * (j0 >> 1);
    const int bc = j0 & 1;
    if (br >= NROW) return;
    const int bm = br * 128, bn = bc * 128;
    const int tid = threadIdx.x, lane = tid & 63, w = tid >> 6;
    const int wr = (w >> 1) * 64, wc = (w & 1) * 64;
    const int sm = tid >> 1, skb = (tid & 1) * 16;
    const bool rok = (bm + sm) < M;
    const int ph0 = (((tid & 1) * 2 + 0) ^ ((sm >> 1) & 3)) << 3;
    const int ph1 = (((tid & 1) * 2 + 1) ^ ((sm >> 1) & 3)) << 3;
    const int lr = lane >> 2, lsl = lane & 3;

    f32x4 acc[4][4] = {};

    for (int k0 = 0; k0 < K; k0 += 32) {
#pragma unroll
        for (int c = 0; c < 2; c++) {
            int rb = (w + c * 4) * 16;
            int row = rb + lr;
            int slg = lsl ^ ((row >> 1) & 3);
            gl_lds16h(BT + (size_t)(bn + row) * K + k0 + slg * 8, sB + rb * 32);
        }
        {
            const float* Arow = A + (size_t)(bm + sm) * lda + k0 + skb;
            float4 v0 = make_float4(0.f, 0.f, 0.f, 0.f), v1 = v0, v2 = v0, v3 = v0;
            if (rok) {
                v0 = *(const float4*)(Arow + 0);
                v1 = *(const float4*)(Arow + 4);
                v2 = *(const float4*)(Arow + 8);
                v3 = *(const float4*)(Arow + 12);
            }
            half8 ha, hb;
            ha[0] = (_Float16)v0.x; ha[1] = (_Float16)v0.y;
            ha[2] = (_Float16)v0.z; ha[3] = (_Float16)v0.w;
            ha[4] = (_Float16)v1.x; ha[5] = (_Float16)v1.y;
            ha[6] = (_Float16)v1.z; ha[7] = (_Float16)v1.w;
            hb[0] = (_Float16)v2.x; hb[1] = (_Float16)v2.y;
            hb[2] = (_Float16)v2.z; hb[3] = (_Float16)v2.w;
            hb[4] = (_Float16)v3.x; hb[5] = (_Float16)v3.y;
            hb[6] = (_Float16)v3.z; hb[7] = (_Float16)v3.w;
            *reinterpret_cast<half8*>(&sA[sm * 32 + ph0]) = ha;
            *reinterpret_cast<half8*>(&sA[sm * 32 + ph1]) = hb;
        }
        __syncthreads();
        half8 af[4], bf[4];
        const int g = lane >> 4, fr = lane & 15;
#pragma unroll
        for (int i = 0; i < 4; i++) {
            int Ra = wr + i * 16 + fr;
            af[i] = *reinterpret_cast<const half8*>(
                &sA[Ra * 32 + ((g ^ ((Ra >> 1) & 3)) << 3)]);
            int Rb = wc + i * 16 + fr;
            bf[i] = *reinterpret_cast<const half8*>(
                &sB[Rb * 32 + ((g ^ ((Rb >> 1) & 3)) << 3)]);
        }
#pragma unroll
        for (int i = 0; i < 4; i++)
#pragma unroll
            for (int j = 0; j < 4; j++)
                acc[i][j] = __builtin_amdgcn_mfma_f32_16x16x32_f16(af[i], bf[j], acc[i][j], 0, 0, 0);
        __syncthreads();
    }
    const int crow0 = (lane >> 4) * 4, ccol = lane & 15;
#pragma unroll
    for (int i = 0; i < 4; i++)
#pragma unroll
        for (int j = 0; j < 4; j++) {
            int cc = bn + wc + j * 16 + ccol;
            float bv = bias[cc];
#pragma unroll
            for (int r = 0; r < 4; r++) {
                int row = bm + wr + i * 16 + crow0 + r;
                if (row < M) {
                    float v = acc[i][j][r] + bv;
                    v = v > 0.f ? v : 0.f;
                    C[(size_t)row * 256 + cc] = __float2half(v);
                }
            }
        }
}

// ---------------------------------------------------------------- scores from h0 (256-wide fp16, layer 1)
__global__ __launch_bounds__(256) void k_score8(const __half* __restrict__ h0,
                                                const float* __restrict__ va,
                                                float* __restrict__ a_s,
                                                float* __restrict__ a_d, int N) {
    __shared__ float sva[8][256];
    int t = threadIdx.x;
    for (int i = t; i < 2048; i += 256) sva[i >> 8][i & 255] = va[i];
    __syncthreads();
    int wv = t >> 6, lane = t & 63;
    int n = blockIdx.x * 4 + wv;
    if (n >= N) return;
    uint2 u = *(const uint2*)(h0 + (size_t)n * 256 + lane * 4);
    __half2 q0 = __builtin_bit_cast(__half2, u.x);
    __half2 q1 = __builtin_bit_cast(__half2, u.y);
    float v0 = __half2float(q0.x), v1 = __half2float(q0.y);
    float v2 = __half2float(q1.x), v3 = __half2float(q1.y);
    float p[8];
#pragma unroll
    for (int v = 0; v < 8; v++) {
        p[v] = v0 * sva[v][lane * 4] + v1 * sva[v][lane * 4 + 1] +
               v2 * sva[v][lane * 4 + 2] + v3 * sva[v][lane * 4 + 3];
    }
#pragma unroll
    for (int off = 32; off > 0; off >>= 1)
#pragma unroll
        for (int v = 0; v < 8; v++) p[v] += __shfl_xor(p[v], off, 64);
    if (lane == 0) {
        *(float4*)&a_s[n * 4] = make_float4(p[0], p[1], p[2], p[3]);
        *(float4*)&a_d[n * 4] = make_float4(p[4], p[5], p[6], p[7]);
    }
}

// ---------------------------------------------------------------- scores from h1 via va2 (layer 2)
__global__ __launch_bounds__(256) void k_score1024(const __half* __restrict__ h1,
                                                   const float* __restrict__ va2,
                                                   float* __restrict__ a_s,
                                                   float* __restrict__ a_d, int N) {
    __shared__ float sva[8 * 1024];
    int t = threadIdx.x;
    for (int i = t; i < 8192; i += 256) sva[i] = va2[i];
    __syncthreads();
    int wv = t >> 6, lane = t & 63;
    int n = blockIdx.x * 4 + wv;
    if (n >= N) return;
    const __half* hp = h1 + (size_t)n * 1024;
    float hv[16];
#pragma unroll
    for (int seg = 0; seg < 4; seg++) {
        half4 u = *reinterpret_cast<const half4*>(hp + seg * 256 + lane * 4);
#pragma unroll
        for (int c = 0; c < 4; c++) hv[seg * 4 + c] = (float)u[c];
    }
    float p[8] = {};
#pragma unroll
    for (int v = 0; v < 8; v++) {
#pragma unroll
        for (int seg = 0; seg < 4; seg++) {
            float4 f = *(const float4*)&sva[v * 1024 + seg * 256 + lane * 4];
            p[v] += hv[seg * 4] * f.x + hv[seg * 4 + 1] * f.y +
                    hv[seg * 4 + 2] * f.z + hv[seg * 4 + 3] * f.w;
        }
    }
#pragma unroll
    for (int off = 32; off > 0; off >>= 1)
#pragma unroll
        for (int v = 0; v < 8; v++) p[v] += __shfl_xor(p[v], off, 64);
    if (lane == 0) {
        *(float4*)&a_s[n * 4] = make_float4(p[0], p[1], p[2], p[3]);
        *(float4*)&a_d[n * 4] = make_float4(p[4], p[5], p[6], p[7]);
    }
}

// ---------------------------------------------------------------- alpha precompute
// One wave per node. Pass A: per-head global max. Pass B: S + write unnormalized
// w=exp(e-M) as half4 at alp[(rowstart[n]+n+i)*4] (i==deg -> self loop);
// invS[n][h] = 1/S. Gathers then need no softmax at all.
__global__ __launch_bounds__(256) void k_alpha(
    const float* __restrict__ a_s, const float* __restrict__ a_d,
    const int* __restrict__ rowstart, const int* __restrict__ col,
    __half* __restrict__ alp, float* __restrict__ invS, int N) {
    const int w = threadIdx.x >> 6, lane = threadIdx.x & 63;
    const int n = blockIdx.x * 4 + w;
    if (n >= N) return;
    const int e0 = rowstart[n];
    const int deg = rowstart[n + 1] - e0;
    const int tot = deg + 1;
    const int as0 = e0 + n;
    float4 adv4 = *(const float4*)&a_d[n * 4];
    const float adv[4] = {adv4.x, adv4.y, adv4.z, adv4.w};
    float M[4] = {-INFINITY, -INFINITY, -INFINITY, -INFINITY};
    // pass A: max
    for (int base = 0; base < tot; base += 64) {
        const int li = base + lane;
        float e[4] = {-INFINITY, -INFINITY, -INFINITY, -INFINITY};
        if (li < tot) {
            const int sn = (li < deg) ? col[e0 + li] : n;
            float4 asv = *(const float4*)&a_s[sn * 4];
            const float as4[4] = {asv.x, asv.y, asv.z, asv.w};
#pragma unroll
            for (int h = 0; h < 4; h++) {
                float sc = as4[h] + adv[h];
                e[h] = sc >= 0.f ? sc : 0.2f * sc;
            }
        }
#pragma unroll
        for (int off = 32; off > 0; off >>= 1)
#pragma unroll
            for (int h = 0; h < 4; h++)
                e[h] = fmaxf(e[h], __shfl_xor(e[h], off, 64));
#pragma unroll
        for (int h = 0; h < 4; h++) M[h] = fmaxf(M[h], e[h]);
    }
    // pass B: sum + write
    float S[4] = {0.f, 0.f, 0.f, 0.f};
    for (int base = 0; base < tot; base += 64) {
        const int li = base + lane;
        float wv[4] = {0.f, 0.f, 0.f, 0.f};
        if (li < tot) {
            const int sn = (li < deg) ? col[e0 + li] : n;
            float4 asv = *(const float4*)&a_s[sn * 4];
            const float as4[4] = {asv.x, asv.y, asv.z, asv.w};
            half4 o;
#pragma unroll
            for (int h = 0; h < 4; h++) {
                float sc = as4[h] + adv[h];
                float e = sc >= 0.f ? sc : 0.2f * sc;
                wv[h] = __expf(e - M[h]);
                o[h] = (_Float16)wv[h];
            }
            *reinterpret_cast<half4*>(alp + (size_t)(as0 + li) * 4) = o;
        }
        float sw[4] = {wv[0], wv[1], wv[2], wv[3]};
#pragma unroll
        for (int off = 32; off > 0; off >>= 1)
#pragma unroll
            for (int h = 0; h < 4; h++) sw[h] += __shfl_xor(sw[h], off, 64);
#pragma unroll
        for (int h = 0; h < 4; h++) S[h] += sw[h];
    }
    if (lane == 0) {
        *(float4*)&invS[n * 4] = make_float4(
            1.f / (S[0] + 1e-16f), 1.f / (S[1] + 1e-16f),
            1.f / (S[2] + 1e-16f), 1.f / (S[3] + 1e-16f));
    }
}

// ---------------------------------------------------------------- layer-1 gather (slice-2, no softmax)
// bid = ng*2 + s; wave: 4-head weighted gather of h0 channels [s*128,+128).
__global__ __launch_bounds__(256) void k_gath1(
    const __half* __restrict__ h0, const __half* __restrict__ alp,
    const float* __restrict__ invS, const int* __restrict__ rowstart,
    const int* __restrict__ col, __half* __restrict__ agg1, int N) {
    __shared__ int wsn[4][64];
    __shared__ float wal[4][64][4];
    const int w = threadIdx.x >> 6, lane = threadIdx.x & 63;
    const int bid = blockIdx.x;
    const int s = bid & 1;
    const int n = (bid >> 1) * 4 + w;
    if (n >= N) return;
    const int e0 = rowstart[n];
    const int deg = rowstart[n + 1] - e0;
    const int tot = deg + 1;
    const int as0 = e0 + n;
    float acc[4][2] = {};

    for (int base = 0; base < tot; base += 64) {
        const int cnt = min(64, tot - base);
        const int li = base + lane;
        if (li < tot) {
            wsn[w][lane] = (li < deg) ? col[e0 + li] : n;
            half4 av = *reinterpret_cast<const half4*>(alp + (size_t)(as0 + li) * 4);
            *(float4*)&wal[w][lane][0] = make_float4(
                (float)av[0], (float)av[1], (float)av[2], (float)av[3]);
        }
        const __half* gbase = h0 + s * 128 + lane * 2;
#pragma unroll 2
        for (int i = 0; i < cnt; i++) {
            const int s2 = wsn[w][i];
            float4 wg = *(const float4*)&wal[w][i][0];
            const float wgt[4] = {wg.x, wg.y, wg.z, wg.w};
            __half2 hv = *(const __half2*)(gbase + (size_t)s2 * 256);
            float v0 = __half2float(hv.x), v1 = __half2float(hv.y);
#pragma unroll
            for (int h = 0; h < 4; h++) {
                acc[h][0] += wgt[h] * v0;
                acc[h][1] += wgt[h] * v1;
            }
        }
    }
    float4 dv = *(const float4*)&invS[n * 4];
    const float d[4] = {dv.x, dv.y, dv.z, dv.w};
#pragma unroll
    for (int h = 0; h < 4; h++) {
        __half2 o;
        o.x = __float2half(acc[h][0] * d[h]);
        o.y = __float2half(acc[h][1] * d[h]);
        *(__half2*)(agg1 + (size_t)n * 1024 + h * 256 + s * 128 + lane * 2) = o;
    }
}

// ---------------------------------------------------------------- layer-2 gather (slice-8, no softmax)
// bid = ng*8 + sl, sl = h*2+half -> XCD sl. Wave gathers hW2 channels
// [h*256+half*128, +128) (half2/lane). Epilogue: *invS + bias, ELU.
__global__ __launch_bounds__(256) void k_gath2(
    const __half* __restrict__ hW, const __half* __restrict__ alp,
    const float* __restrict__ invS, const int* __restrict__ rowstart,
    const int* __restrict__ col, const float* __restrict__ bias,
    __half* __restrict__ h2, int N) {
    __shared__ int wsn[4][64];
    __shared__ float wal[4][64];
    const int w = threadIdx.x >> 6, lane = threadIdx.x & 63;
    const int bid = blockIdx.x;
    const int sl = bid & 7;
    const int h = sl >> 1, half = sl & 1;
    const int n = (bid >> 3) * 4 + w;
    if (n >= N) return;
    const int e0 = rowstart[n];
    const int deg = rowstart[n + 1] - e0;
    const int tot = deg + 1;
    const int as0 = e0 + n;
    float a0 = 0.f, a1 = 0.f;

    for (int base = 0; base < tot; base += 64) {
        const int cnt = min(64, tot - base);
        const int li = base + lane;
        if (li < tot) {
            wsn[w][lane] = (li < deg) ? col[e0 + li] : n;
            wal[w][lane] = (float)alp[(size_t)(as0 + li) * 4 + h];
        }
        const __half* gbase = hW + h * 256 + half * 128 + lane * 2;
#pragma unroll 4
        for (int i = 0; i < cnt; i++) {
            const int s2 = wsn[w][i];
            const float a = wal[w][i];
            __half2 v = *(const __half2*)(gbase + (size_t)s2 * 1024);
            a0 += a * __half2float(v.x);
            a1 += a * __half2float(v.y);
        }
    }
    const float d = invS[n * 4 + h];
    const int cc = h * 256 + half * 128 + lane * 2;
    float2 bb = *(const float2*)&bias[cc];
    float v0 = a0 * d + bb.x;
    float v1 = a1 * d + bb.y;
    v0 = v0 > 0.f ? v0 : (__expf(v0) - 1.f);
    v1 = v1 > 0.f ? v1 : (__expf(v1) - 1.f);
    __half2 o;
    o.x = __float2half(v0);
    o.y = __float2half(v1);
    *(__half2*)(h2 + (size_t)n * 1024 + cc) = o;
}

// ---------------------------------------------------------------- pooling (two-stage)
__global__ __launch_bounds__(128) void k_gbounds(const int* __restrict__ batch, int N,
                                                 int* __restrict__ gstart) {
    int g = threadIdx.x;
    if (g > N_GRAPHS) return;
    if (g == N_GRAPHS) { gstart[N_GRAPHS] = N; return; }
    int lo = 0, hi = N;
    while (lo < hi) {
        int mid = (lo + hi) >> 1;
        if (batch[mid] < g) lo = mid + 1; else hi = mid;
    }
    gstart[g] = lo;
}

__global__ __launch_bounds__(256) void k_pool1(const __half* __restrict__ h,
                                               const int* __restrict__ gstart,
                                               float* __restrict__ ps) {
    const int g = blockIdx.x, c = blockIdx.y, t = threadIdx.x;
    const int s = gstart[g], e = gstart[g + 1];
    const int len = e - s;
    const int cs = s + (int)(((long long)len * c) >> 3);
    const int ce = s + (int)(((long long)len * (c + 1)) >> 3);
    float sum[4] = {};
    float mx[4] = {-INFINITY, -INFINITY, -INFINITY, -INFINITY};
    for (int i = cs; i < ce; i++) {
        half4 v = *reinterpret_cast<const half4*>(h + (size_t)i * N_HC + t * 4);
#pragma unroll
        for (int k = 0; k < 4; k++) {
            float f = (float)v[k];
            sum[k] += f;
            mx[k] = fmaxf(mx[k], f);
        }
    }
    float* o = ps + ((size_t)g * 8 + c) * 2048;
    *(float4*)&o[t * 4] = make_float4(sum[0], sum[1], sum[2], sum[3]);
    *(float4*)&o[1024 + t * 4] = make_float4(mx[0], mx[1], mx[2], mx[3]);
}

__global__ __launch_bounds__(256) void k_pool2(const float* __restrict__ ps,
                                               const int* __restrict__ gstart,
                                               float* __restrict__ gout) {
    const int g = blockIdx.x, t = threadIdx.x;
    float sum[4] = {};
    float mx[4] = {-INFINITY, -INFINITY, -INFINITY, -INFINITY};
#pragma unroll
    for (int c = 0; c < 8; c++) {
        const float* o = ps + ((size_t)g * 8 + c) * 2048;
        float4 sv = *(const float4*)&o[t * 4];
        float4 mv = *(const float4*)&o[1024 + t * 4];
        sum[0] += sv.x; sum[1] += sv.y; sum[2] += sv.z; sum[3] += sv.w;
        mx[0] = fmaxf(mx[0], mv.x); mx[1] = fmaxf(mx[1], mv.y);
        mx[2] = fmaxf(mx[2], mv.z); mx[3] = fmaxf(mx[3], mv.w);
    }
    float cnt = fmaxf((float)(gstart[g + 1] - gstart[g]), 1.f);
    float inv = 1.f / cnt;
    *(float4*)(gout + (size_t)g * 2048 + t * 4) =
        make_float4(sum[0] * inv, sum[1] * inv, sum[2] * inv, sum[3] * inv);
    *(float4*)(gout + (size_t)g * 2048 + 1024 + t * 4) =
        make_float4(mx[0], mx[1], mx[2], mx[3]);
}

// ---------------------------------------------------------------- classifier
__global__ __launch_bounds__(256) void k_cls1(const float* __restrict__ g,
                                              const float* __restrict__ Wc1,
                                              const float* __restrict__ bc1,
                                              float* __restrict__ hcls) {
    __shared__ float gs[2048];
    int gb = blockIdx.x, t = threadIdx.x;
    for (int i = t; i < 2048; i += 256) gs[i] = g[(size_t)gb * 2048 + i];
    __syncthreads();
    float acc = 0.f;
    for (int k = 0; k < 2048; k++) acc += gs[k] * Wc1[(size_t)k * 256 + t];
    float v = acc + bc1[t];
    hcls[gb * 256 + t] = v > 0.f ? v : 0.f;
}

__global__ __launch_bounds__(256) void k_cls2(const float* __restrict__ hcls,
                                              const float* __restrict__ Wc2,
                                              const float* __restrict__ bc2,
                                              float* __restrict__ out) {
    int idx = blockIdx.x * 256 + threadIdx.x;
    if (idx >= N_GRAPHS * 5) return;
    int gb = idx / 5, j = idx % 5;
    float acc = 0.f;
    for (int k = 0; k < 256; k++) acc += hcls[gb * 256 + k] * Wc2[k * 5 + j];
    out[idx] = acc + bc2[j];
}

// ---------------------------------------------------------------- launch
extern "C" void kernel_launch(void* const* d_in, const int* in_sizes, int n_in,
                              void* d_out, int out_size, void* d_ws, size_t ws_size,
                              hipStream_t stream) {
    const float* x    = (const float*)d_in[0];
    const int*   ei   = (const int*)d_in[1];
    const int*   batch= (const int*)d_in[2];
    const float* Wp   = (const float*)d_in[3];
    const float* bp   = (const float*)d_in[4];
    const float* W1   = (const float*)d_in[5];
    const float* as1  = (const float*)d_in[6];
    const float* ad1  = (const float*)d_in[7];
    const float* b1   = (const float*)d_in[8];
    const float* W2   = (const float*)d_in[9];
    const float* as2  = (const float*)d_in[10];
    const float* ad2  = (const float*)d_in[11];
    const float* b2   = (const float*)d_in[12];
    const float* Wc1  = (const float*)d_in[13];
    const float* bc1  = (const float*)d_in[14];
    const float* Wc2  = (const float*)d_in[15];
    const float* bc2  = (const float*)d_in[16];
    float* out = (float*)d_out;

    const int N = in_sizes[0] / 768;   // 20000
    const int E = in_sizes[1] / 2;     // 320000
    const int MP = ((N + 127) / 128) * 128;   // 20096
    const int MB = MP / 128;                  // 157

    const int* src = ei;
    const int* dst = ei + E;

    char* ws = (char*)d_ws;
    size_t off = 0;
    auto give = [&](size_t bytes) -> void* {
        void* p = ws + off;
        off = (off + bytes + 255) & ~(size_t)255;
        return p;
    };
    __half* h0  = (__half*)give((size_t)MP * N_HID * 2);
    __half* agg1= (__half*)give((size_t)MP * N_HC * 2);
    __half* h1  = (__half*)give((size_t)MP * N_HC * 2);
    __half* hW2 = (__half*)give((size_t)MP * N_HC * 2);
    __half* h2  = (__half*)give((size_t)MP * N_HC * 2);
    __half* WpT = (__half*)give((size_t)768 * 256 * 2);
    __half* W1T = (__half*)give((size_t)256 * 1024 * 2);
    __half* W2T = (__half*)give((size_t)1024 * 1024 * 2);
    float* va   = (float*)give((size_t)8 * 256 * 4);
    float* va2  = (float*)give((size_t)8 * 1024 * 4);
    float* a_s1 = (float*)give((size_t)N * N_HEADS * 4);
    float* a_d1 = (float*)give((size_t)N * N_HEADS * 4);
    float* a_s2 = (float*)give((size_t)N * N_HEADS * 4);
    float* a_d2 = (float*)give((size_t)N * N_HEADS * 4);
    __half* alp1 = (__half*)give((size_t)(E + N) * 4 * 2);   // 2.72 MB
    __half* alp2 = (__half*)give((size_t)(E + N) * 4 * 2);
    float* invS1 = (float*)give((size_t)N * 4 * 4);
    float* invS2 = (float*)give((size_t)N * 4 * 4);
    float* ps   = (float*)give((size_t)N_GRAPHS * 8 * 2048 * 4);
    int* deg     = (int*)give((size_t)N * 4);
    int* cursor  = (int*)give((size_t)N * 4);
    int* rowstart= (int*)give((size_t)(N + 1) * 4);
    int* col     = (int*)give((size_t)E * 4);
    int* gstart  = (int*)give((size_t)(N_GRAPHS + 1) * 4);
    float* gpool = (float*)give((size_t)N_GRAPHS * 2048 * 4);
    float* hcls  = (float*)give((size_t)N_GRAPHS * 256 * 4);
    (void)ws_size; (void)n_in; (void)out_size;

    // ---- CSR + prep
    hipMemsetAsync(deg, 0, (size_t)N * 4, stream);
    hipMemsetAsync(cursor, 0, (size_t)N * 4, stream);
    hipMemsetAsync(va2, 0, (size_t)8 * 1024 * 4, stream);
    k_deg<<<(E + 255) / 256, 256, 0, stream>>>(dst, E, deg);
    k_scan<<<1, 1024, 0, stream>>>(deg, rowstart, N);
    k_fill<<<(E + 255) / 256, 256, 0, stream>>>(src, dst, E, rowstart, cursor, col);
    k_gbounds<<<1, 128, 0, stream>>>(batch, N, gstart);

    k_wtt<<<dim3(256 / 32, 768 / 32), 256, 0, stream>>>(Wp, WpT, 768, 256);
    k_wtt<<<dim3(1024 / 32, 256 / 32), 256, 0, stream>>>(W1, W1T, 256, 1024);
    k_wtt<<<dim3(1024 / 32, 1024 / 32), 256, 0, stream>>>(W2, W2T, 1024, 1024);
    k_makeva<<<8, 256, 0, stream>>>(W1T, as1, ad1, va);
    k_makeva2<<<dim3(8, 8), 256, 0, stream>>>(W2T, as2, ad2, va2);

    const int NROWPAD = ((MB + 7) / 8) * 8;   // 160
    const int NGB = (N + 3) / 4;

    // ---- h0 = relu(x @ WpT + bp) fp16
    k_gemm_x<<<NROWPAD * 2, 256, 0, stream>>>(x, WpT, bp, h0, N, MB, 768, 768);

    // ---- layer 1: scores -> alpha -> gather (slice-2) -> per-head transform
    k_score8<<<NGB, 256, 0, stream>>>(h0, va, a_s1, a_d1, N);
    k_alpha<<<NGB, 256, 0, stream>>>(a_s1, a_d1, rowstart, col, alp1, invS1, N);
    k_gath1<<<NGB * 2, 256, 0, stream>>>(h0, alp1, invS1, rowstart, col, agg1, N);
    k_gemm2p<2, 0><<<dim3(2, MB, 4), 256, 0, stream>>>(
        agg1, W1T, b1, h1, N, 0, 256, 1024, 1024, 256, 65536, 256, 256);

    // ---- layer 2: scores (va2) -> alpha; W2 GEMM; gather (slice-8)
    k_score1024<<<NGB, 256, 0, stream>>>(h1, va2, a_s2, a_d2, N);
    k_alpha<<<NGB, 256, 0, stream>>>(a_s2, a_d2, rowstart, col, alp2, invS2, N);
    k_gemm2p<0, 1><<<NROWPAD * 8, 256, 0, stream>>>(
        h1, W2T, nullptr, hW2, N, MB, 1024, 1024, 1024, 0, 0, 0, 0);
    k_gath2<<<NGB * 8, 256, 0, stream>>>(
        hW2, alp2, invS2, rowstart, col, b2, h2, N);

    // ---- pooling (two-stage) + classifier
    k_pool1<<<dim3(N_GRAPHS, 8), 256, 0, stream>>>(h2, gstart, ps);
    k_pool2<<<N_GRAPHS, 256, 0, stream>>>(ps, gstart, gpool);
    k_cls1<<<N_GRAPHS, 256, 0, stream>>>(gpool, Wc1, bc1, hcls);
    k_cls2<<<2, 256, 0, stream>>>(hcls, Wc2, bc2, out);
}

// Round 15
// 475.660 us; speedup vs baseline: 1.0498x; 1.0498x over previous
//
#include <hip/hip_runtime.h>
#include <hip/hip_fp16.h>
#include <math.h>

#define N_HID 256
#define N_HEADS 4
#define N_HC 1024
#define N_GRAPHS 64

typedef __attribute__((ext_vector_type(4))) float f32x4;
typedef _Float16 half8 __attribute__((ext_vector_type(8)));
typedef _Float16 half4 __attribute__((ext_vector_type(4)));

__device__ __forceinline__ void gl_lds16h(const __half* g, __half* l) {
    __builtin_amdgcn_global_load_lds(
        (const __attribute__((address_space(1))) unsigned int*)g,
        (__attribute__((address_space(3))) unsigned int*)l, 16, 0, 0);
}

// ---------------------------------------------------------------- CSR build
__global__ __launch_bounds__(256) void k_deg(const int* __restrict__ dst, int E,
                                             int* __restrict__ deg) {
    int e = blockIdx.x * 256 + threadIdx.x;
    if (e < E) atomicAdd(&deg[dst[e]], 1);
}

__global__ __launch_bounds__(1024) void k_scan(const int* __restrict__ deg,
                                               int* __restrict__ rowstart, int N) {
    __shared__ int part[1024];
    const int t = threadIdx.x;
    const int chunk = (N + 1023) / 1024;
    const int c0 = t * chunk;
    int s = 0;
    for (int i = 0; i < chunk; i++) {
        int idx = c0 + i;
        if (idx < N) s += deg[idx];
    }
    part[t] = s;
    __syncthreads();
    for (int off = 1; off < 1024; off <<= 1) {
        int v = (t >= off) ? part[t - off] : 0;
        __syncthreads();
        part[t] += v;
        __syncthreads();
    }
    int run = (t == 0) ? 0 : part[t - 1];
    if (t == 0) rowstart[0] = 0;
    for (int i = 0; i < chunk; i++) {
        int idx = c0 + i;
        if (idx < N) {
            run += deg[idx];
            rowstart[idx + 1] = run;
        }
    }
}

__global__ __launch_bounds__(256) void k_fill(const int* __restrict__ src,
                                              const int* __restrict__ dst, int E,
                                              const int* __restrict__ rowstart,
                                              int* __restrict__ cursor,
                                              int* __restrict__ col) {
    int e = blockIdx.x * 256 + threadIdx.x;
    if (e < E) {
        int d = dst[e];
        int p = atomicAdd(&cursor[d], 1);
        col[rowstart[d] + p] = src[e];
    }
}

// ---------------------------------------------------------------- tiled transpose fp32[K][N] -> fp16[N][K]
__global__ __launch_bounds__(256) void k_wtt(const float* __restrict__ W,
                                             __half* __restrict__ WT, int K, int N) {
    __shared__ float tile[32][33];
    const int k0 = blockIdx.y * 32, n0 = blockIdx.x * 32;
    const int tr = threadIdx.x >> 5, tc = threadIdx.x & 31;
#pragma unroll
    for (int rr = 0; rr < 4; rr++) {
        int k = k0 + tr + rr * 8;
        tile[tr + rr * 8][tc] = W[(size_t)k * N + n0 + tc];
    }
    __syncthreads();
#pragma unroll
    for (int rr = 0; rr < 4; rr++) {
        int n = n0 + tr + rr * 8;
        WT[(size_t)n * K + k0 + tc] = __float2half(tile[tc][tr + rr * 8]);
    }
}

// ---------------------------------------------------------------- va = W1_h @ att_h (layer 1, from W1T fp16)
__global__ __launch_bounds__(256) void k_makeva(const __half* __restrict__ W1T,
                                                const float* __restrict__ as1,
                                                const float* __restrict__ ad1,
                                                float* __restrict__ va) {
    __shared__ float satt[256];
    int b = blockIdx.x;       // 0..7
    int h = b & 3, isd = b >> 2;
    int k = threadIdx.x;      // 0..255
    const float* att = (isd ? ad1 : as1) + h * 256;
    satt[k] = att[k];
    __syncthreads();
    const __half* wr = W1T + (size_t)(h * 256) * 256 + k;
    float s = 0.f;
    for (int c = 0; c < 256; c++) s += __half2float(wr[(size_t)c * 256]) * satt[c];
    va[b * 256 + k] = s;
}

// ---------------------------------------------------------------- va2 = W2_h^T @ att2_h (layer 2, chunked + atomic)
__global__ __launch_bounds__(256) void k_makeva2(const __half* __restrict__ W2T,
                                                 const float* __restrict__ as2,
                                                 const float* __restrict__ ad2,
                                                 float* __restrict__ va2) {
    __shared__ float satt[32];
    int b = blockIdx.x;   // 0..7
    int h = b & 3;
    int jc = blockIdx.y;  // 0..7
    int t = threadIdx.x;
    const float* att = (b >= 4 ? ad2 : as2) + h * 256 + jc * 32;
    if (t < 32) satt[t] = att[t];
    __syncthreads();
    float s0 = 0.f, s1 = 0.f, s2 = 0.f, s3 = 0.f;
    const __half* base = W2T + (size_t)(h * 256 + jc * 32) * 1024 + t * 4;
    for (int j = 0; j < 32; j++) {
        half4 wv = *reinterpret_cast<const half4*>(base + (size_t)j * 1024);
        float a = satt[j];
        s0 += a * (float)wv[0]; s1 += a * (float)wv[1];
        s2 += a * (float)wv[2]; s3 += a * (float)wv[3];
    }
    float* o = va2 + b * 1024 + t * 4;
    atomicAdd(o + 0, s0); atomicAdd(o + 1, s1);
    atomicAdd(o + 2, s2); atomicAdd(o + 3, s3);
}

// ---------------------------------------------------------------- 2-phase dbuf fp16 MFMA GEMM (BK=32)
template <int EPI, int COSCHED>
__global__ __launch_bounds__(256) void k_gemm2p(
    const __half* __restrict__ A, const __half* __restrict__ BT,
    const float* __restrict__ bias, __half* __restrict__ C,
    int M, int NROW, int K, int lda, int ldc,
    int aoffz, int boffz, int coffz, int bofz) {
    __shared__ __half sA[2][128 * 32];
    __shared__ __half sB[2][128 * 32];
    int bm, bn;
    size_t coff = 0;
    if (COSCHED) {
        const int bid = blockIdx.x;
        const int xcd = bid & 7, j0 = bid >> 3;
        const int br = xcd + 8 * (j0 >> 3);
        const int bc = j0 & 7;
        if (br >= NROW) return;
        bm = br * 128; bn = bc * 128;
    } else {
        const int z = blockIdx.z;
        A += (size_t)z * aoffz;
        BT += (size_t)z * boffz;
        bias += z * bofz;
        coff = (size_t)z * coffz;
        bm = blockIdx.y * 128; bn = blockIdx.x * 128;
    }
    const int tid = threadIdx.x, lane = tid & 63, w = tid >> 6;
    const int wr = (w >> 1) * 64, wc = (w & 1) * 64;
    const bool isB = (w >= 2);
    const __half* gsrc = isB ? (BT + (size_t)bn * K) : (A + (size_t)bm * lda);
    const int gld = isB ? K : lda;
    const int rbase = (w & 1) * 64;
    const int lr = lane >> 2, lsl = lane & 3;
    const int g = lane >> 4, fr = lane & 15;
    const int nt = K >> 5;

    f32x4 acc[4][4] = {};

    auto STAGE = [&](int b, int t) {
        __half* sbuf = (isB ? sB[b] : sA[b]);
        const int k0 = t << 5;
#pragma unroll
        for (int c2 = 0; c2 < 4; c2++) {
            int row = rbase + c2 * 16 + lr;
            int slg = lsl ^ ((row >> 1) & 3);
            gl_lds16h(gsrc + (size_t)row * gld + k0 + slg * 8,
                      sbuf + (rbase + c2 * 16) * 32);
        }
    };

    STAGE(0, 0);
    int cur = 0;
    for (int t = 0; t < nt; ++t) {
        if (t + 1 < nt) {
            STAGE(cur ^ 1, t + 1);
            asm volatile("s_waitcnt vmcnt(4)" ::: "memory");
        } else {
            asm volatile("s_waitcnt vmcnt(0)" ::: "memory");
        }
        asm volatile("s_barrier" ::: "memory");
        half8 af[4], bf[4];
#pragma unroll
        for (int i = 0; i < 4; i++) {
            int Ra = wr + i * 16 + fr;
            af[i] = *reinterpret_cast<const half8*>(
                &sA[cur][Ra * 32 + ((g ^ ((Ra >> 1) & 3)) << 3)]);
            int Rb = wc + i * 16 + fr;
            bf[i] = *reinterpret_cast<const half8*>(
                &sB[cur][Rb * 32 + ((g ^ ((Rb >> 1) & 3)) << 3)]);
        }
#pragma unroll
        for (int i = 0; i < 4; i++)
#pragma unroll
            for (int j = 0; j < 4; j++)
                acc[i][j] = __builtin_amdgcn_mfma_f32_16x16x32_f16(af[i], bf[j], acc[i][j], 0, 0, 0);
        asm volatile("s_barrier" ::: "memory");
        cur ^= 1;
    }
    const int crow0 = (lane >> 4) * 4, ccol = lane & 15;
#pragma unroll
    for (int i = 0; i < 4; i++)
#pragma unroll
        for (int j = 0; j < 4; j++) {
            int cc = bn + wc + j * 16 + ccol;
            float bv = (EPI == 2) ? bias[cc] : 0.f;
#pragma unroll
            for (int r = 0; r < 4; r++) {
                int row = bm + wr + i * 16 + crow0 + r;
                if (row < M) {
                    float v = acc[i][j][r];
                    if (EPI == 2) { v += bv; v = v > 0.f ? v : (__expf(v) - 1.f); }
                    C[(size_t)row * ldc + coff + cc] = __float2half(v);
                }
            }
        }
}

// ---------------------------------------------------------------- fp32-A MFMA GEMM (fused convert), bias+relu
__global__ __launch_bounds__(256) void k_gemm_x(
    const float* __restrict__ A, const __half* __restrict__ BT,
    const float* __restrict__ bias, __half* __restrict__ C,
    int M, int NROW, int K, int lda) {
    __shared__ __half sA[128 * 32];
    __shared__ __half sB[128 * 32];
    const int bid = blockIdx.x;
    const int xcd = bid & 7, j0 = bid >> 3;
    const int br = xcd + 8 * (j0 >> 1);
    const int bc = j0 & 1;
    if (br >= NROW) return;
    const int bm = br * 128, bn = bc * 128;
    const int tid = threadIdx.x, lane = tid & 63, w = tid >> 6;
    const int wr = (w >> 1) * 64, wc = (w & 1) * 64;
    const int sm = tid >> 1, skb = (tid & 1) * 16;
    const bool rok = (bm + sm) < M;
    const int ph0 = (((tid & 1) * 2 + 0) ^ ((sm >> 1) & 3)) << 3;
    const int ph1 = (((tid & 1) * 2 + 1) ^ ((sm >> 1) & 3)) << 3;
    const int lr = lane >> 2, lsl = lane & 3;

    f32x4 acc[4][4] = {};

    for (int k0 = 0; k0 < K; k0 += 32) {
#pragma unroll
        for (int c = 0; c < 2; c++) {
            int rb = (w + c * 4) * 16;
            int row = rb + lr;
            int slg = lsl ^ ((row >> 1) & 3);
            gl_lds16h(BT + (size_t)(bn + row) * K + k0 + slg * 8, sB + rb * 32);
        }
        {
            const float* Arow = A + (size_t)(bm + sm) * lda + k0 + skb;
            float4 v0 = make_float4(0.f, 0.f, 0.f, 0.f), v1 = v0, v2 = v0, v3 = v0;
            if (rok) {
                v0 = *(const float4*)(Arow + 0);
                v1 = *(const float4*)(Arow + 4);
                v2 = *(const float4*)(Arow + 8);
                v3 = *(const float4*)(Arow + 12);
            }
            half8 ha, hb;
            ha[0] = (_Float16)v0.x; ha[1] = (_Float16)v0.y;
            ha[2] = (_Float16)v0.z; ha[3] = (_Float16)v0.w;
            ha[4] = (_Float16)v1.x; ha[5] = (_Float16)v1.y;
            ha[6] = (_Float16)v1.z; ha[7] = (_Float16)v1.w;
            hb[0] = (_Float16)v2.x; hb[1] = (_Float16)v2.y;
            hb[2] = (_Float16)v2.z; hb[3] = (_Float16)v2.w;
            hb[4] = (_Float16)v3.x; hb[5] = (_Float16)v3.y;
            hb[6] = (_Float16)v3.z; hb[7] = (_Float16)v3.w;
            *reinterpret_cast<half8*>(&sA[sm * 32 + ph0]) = ha;
            *reinterpret_cast<half8*>(&sA[sm * 32 + ph1]) = hb;
        }
        __syncthreads();
        half8 af[4], bf[4];
        const int g = lane >> 4, fr = lane & 15;
#pragma unroll
        for (int i = 0; i < 4; i++) {
            int Ra = wr + i * 16 + fr;
            af[i] = *reinterpret_cast<const half8*>(
                &sA[Ra * 32 + ((g ^ ((Ra >> 1) & 3)) << 3)]);
            int Rb = wc + i * 16 + fr;
            bf[i] = *reinterpret_cast<const half8*>(
                &sB[Rb * 32 + ((g ^ ((Rb >> 1) & 3)) << 3)]);
        }
#pragma unroll
        for (int i = 0; i < 4; i++)
#pragma unroll
            for (int j = 0; j < 4; j++)
                acc[i][j] = __builtin_amdgcn_mfma_f32_16x16x32_f16(af[i], bf[j], acc[i][j], 0, 0, 0);
        __syncthreads();
    }
    const int crow0 = (lane >> 4) * 4, ccol = lane & 15;
#pragma unroll
    for (int i = 0; i < 4; i++)
#pragma unroll
        for (int j = 0; j < 4; j++) {
            int cc = bn + wc + j * 16 + ccol;
            float bv = bias[cc];
#pragma unroll
            for (int r = 0; r < 4; r++) {
                int row = bm + wr + i * 16 + crow0 + r;
                if (row < M) {
                    float v = acc[i][j][r] + bv;
                    v = v > 0.f ? v : 0.f;
                    C[(size_t)row * 256 + cc] = __float2half(v);
                }
            }
        }
}

// ---------------------------------------------------------------- scores from h0 (256-wide fp16, layer 1)
__global__ __launch_bounds__(256) void k_score8(const __half* __restrict__ h0,
                                                const float* __restrict__ va,
                                                float* __restrict__ a_s,
                                                float* __restrict__ a_d, int N) {
    __shared__ float sva[8][256];
    int t = threadIdx.x;
    for (int i = t; i < 2048; i += 256) sva[i >> 8][i & 255] = va[i];
    __syncthreads();
    int wv = t >> 6, lane = t & 63;
    int n = blockIdx.x * 4 + wv;
    if (n >= N) return;
    uint2 u = *(const uint2*)(h0 + (size_t)n * 256 + lane * 4);
    __half2 q0 = __builtin_bit_cast(__half2, u.x);
    __half2 q1 = __builtin_bit_cast(__half2, u.y);
    float v0 = __half2float(q0.x), v1 = __half2float(q0.y);
    float v2 = __half2float(q1.x), v3 = __half2float(q1.y);
    float p[8];
#pragma unroll
    for (int v = 0; v < 8; v++) {
        p[v] = v0 * sva[v][lane * 4] + v1 * sva[v][lane * 4 + 1] +
               v2 * sva[v][lane * 4 + 2] + v3 * sva[v][lane * 4 + 3];
    }
#pragma unroll
    for (int off = 32; off > 0; off >>= 1)
#pragma unroll
        for (int v = 0; v < 8; v++) p[v] += __shfl_xor(p[v], off, 64);
    if (lane == 0) {
        *(float4*)&a_s[n * 4] = make_float4(p[0], p[1], p[2], p[3]);
        *(float4*)&a_d[n * 4] = make_float4(p[4], p[5], p[6], p[7]);
    }
}

// ---------------------------------------------------------------- scores from h1 via va2 (layer 2)
__global__ __launch_bounds__(256) void k_score1024(const __half* __restrict__ h1,
                                                   const float* __restrict__ va2,
                                                   float* __restrict__ a_s,
                                                   float* __restrict__ a_d, int N) {
    __shared__ float sva[8 * 1024];
    int t = threadIdx.x;
    for (int i = t; i < 8192; i += 256) sva[i] = va2[i];
    __syncthreads();
    int wv = t >> 6, lane = t & 63;
    int n = blockIdx.x * 4 + wv;
    if (n >= N) return;
    const __half* hp = h1 + (size_t)n * 1024;
    float hv[16];
#pragma unroll
    for (int seg = 0; seg < 4; seg++) {
        half4 u = *reinterpret_cast<const half4*>(hp + seg * 256 + lane * 4);
#pragma unroll
        for (int c = 0; c < 4; c++) hv[seg * 4 + c] = (float)u[c];
    }
    float p[8] = {};
#pragma unroll
    for (int v = 0; v < 8; v++) {
#pragma unroll
        for (int seg = 0; seg < 4; seg++) {
            float4 f = *(const float4*)&sva[v * 1024 + seg * 256 + lane * 4];
            p[v] += hv[seg * 4] * f.x + hv[seg * 4 + 1] * f.y +
                    hv[seg * 4 + 2] * f.z + hv[seg * 4 + 3] * f.w;
        }
    }
#pragma unroll
    for (int off = 32; off > 0; off >>= 1)
#pragma unroll
        for (int v = 0; v < 8; v++) p[v] += __shfl_xor(p[v], off, 64);
    if (lane == 0) {
        *(float4*)&a_s[n * 4] = make_float4(p[0], p[1], p[2], p[3]);
        *(float4*)&a_d[n * 4] = make_float4(p[4], p[5], p[6], p[7]);
    }
}

// ---------------------------------------------------------------- alpha precompute
__global__ __launch_bounds__(256) void k_alpha(
    const float* __restrict__ a_s, const float* __restrict__ a_d,
    const int* __restrict__ rowstart, const int* __restrict__ col,
    __half* __restrict__ alp, float* __restrict__ invS, int N) {
    const int w = threadIdx.x >> 6, lane = threadIdx.x & 63;
    const int n = blockIdx.x * 4 + w;
    if (n >= N) return;
    const int e0 = rowstart[n];
    const int deg = rowstart[n + 1] - e0;
    const int tot = deg + 1;
    const int as0 = e0 + n;
    float4 adv4 = *(const float4*)&a_d[n * 4];
    const float adv[4] = {adv4.x, adv4.y, adv4.z, adv4.w};
    float M[4] = {-INFINITY, -INFINITY, -INFINITY, -INFINITY};
    for (int base = 0; base < tot; base += 64) {
        const int li = base + lane;
        float e[4] = {-INFINITY, -INFINITY, -INFINITY, -INFINITY};
        if (li < tot) {
            const int sn = (li < deg) ? col[e0 + li] : n;
            float4 asv = *(const float4*)&a_s[sn * 4];
            const float as4[4] = {asv.x, asv.y, asv.z, asv.w};
#pragma unroll
            for (int h = 0; h < 4; h++) {
                float sc = as4[h] + adv[h];
                e[h] = sc >= 0.f ? sc : 0.2f * sc;
            }
        }
#pragma unroll
        for (int off = 32; off > 0; off >>= 1)
#pragma unroll
            for (int h = 0; h < 4; h++)
                e[h] = fmaxf(e[h], __shfl_xor(e[h], off, 64));
#pragma unroll
        for (int h = 0; h < 4; h++) M[h] = fmaxf(M[h], e[h]);
    }
    float S[4] = {0.f, 0.f, 0.f, 0.f};
    for (int base = 0; base < tot; base += 64) {
        const int li = base + lane;
        float wv[4] = {0.f, 0.f, 0.f, 0.f};
        if (li < tot) {
            const int sn = (li < deg) ? col[e0 + li] : n;
            float4 asv = *(const float4*)&a_s[sn * 4];
            const float as4[4] = {asv.x, asv.y, asv.z, asv.w};
            half4 o;
#pragma unroll
            for (int h = 0; h < 4; h++) {
                float sc = as4[h] + adv[h];
                float e = sc >= 0.f ? sc : 0.2f * sc;
                wv[h] = __expf(e - M[h]);
                o[h] = (_Float16)wv[h];
            }
            *reinterpret_cast<half4*>(alp + (size_t)(as0 + li) * 4) = o;
        }
        float sw[4] = {wv[0], wv[1], wv[2], wv[3]};
#pragma unroll
        for (int off = 32; off > 0; off >>= 1)
#pragma unroll
            for (int h = 0; h < 4; h++) sw[h] += __shfl_xor(sw[h], off, 64);
#pragma unroll
        for (int h = 0; h < 4; h++) S[h] += sw[h];
    }
    if (lane == 0) {
        *(float4*)&invS[n * 4] = make_float4(
            1.f / (S[0] + 1e-16f), 1.f / (S[1] + 1e-16f),
            1.f / (S[2] + 1e-16f), 1.f / (S[3] + 1e-16f));
    }
}

// ---------------------------------------------------------------- layer-1 gather (slice-2, no softmax)
__global__ __launch_bounds__(256) void k_gath1(
    const __half* __restrict__ h0, const __half* __restrict__ alp,
    const float* __restrict__ invS, const int* __restrict__ rowstart,
    const int* __restrict__ col, __half* __restrict__ agg1, int N) {
    __shared__ int wsn[4][64];
    __shared__ float wal[4][64][4];
    const int w = threadIdx.x >> 6, lane = threadIdx.x & 63;
    const int bid = blockIdx.x;
    const int s = bid & 1;
    const int n = (bid >> 1) * 4 + w;
    if (n >= N) return;
    const int e0 = rowstart[n];
    const int deg = rowstart[n + 1] - e0;
    const int tot = deg + 1;
    const int as0 = e0 + n;
    float acc[4][2] = {};

    for (int base = 0; base < tot; base += 64) {
        const int cnt = min(64, tot - base);
        const int li = base + lane;
        if (li < tot) {
            wsn[w][lane] = (li < deg) ? col[e0 + li] : n;
            half4 av = *reinterpret_cast<const half4*>(alp + (size_t)(as0 + li) * 4);
            *(float4*)&wal[w][lane][0] = make_float4(
                (float)av[0], (float)av[1], (float)av[2], (float)av[3]);
        }
        const __half* gbase = h0 + s * 128 + lane * 2;
#pragma unroll 2
        for (int i = 0; i < cnt; i++) {
            const int s2 = wsn[w][i];
            float4 wg = *(const float4*)&wal[w][i][0];
            const float wgt[4] = {wg.x, wg.y, wg.z, wg.w};
            __half2 hv = *(const __half2*)(gbase + (size_t)s2 * 256);
            float v0 = __half2float(hv.x), v1 = __half2float(hv.y);
#pragma unroll
            for (int h = 0; h < 4; h++) {
                acc[h][0] += wgt[h] * v0;
                acc[h][1] += wgt[h] * v1;
            }
        }
    }
    float4 dv = *(const float4*)&invS[n * 4];
    const float d[4] = {dv.x, dv.y, dv.z, dv.w};
#pragma unroll
    for (int h = 0; h < 4; h++) {
        __half2 o;
        o.x = __float2half(acc[h][0] * d[h]);
        o.y = __float2half(acc[h][1] * d[h]);
        *(__half2*)(agg1 + (size_t)n * 1024 + h * 256 + s * 128 + lane * 2) = o;
    }
}

// ---------------------------------------------------------------- layer-2 gather (slice-4 head-affine, no softmax)
// bid = ng*4 + h -> head h on XCDs {h, h+4}. Wave owns head h's 256 channels
// (half4/lane, 8B). Inner loop: 1 load + 4 cvt + 4 FMA per edge.
__global__ __launch_bounds__(256) void k_gath2(
    const __half* __restrict__ hW, const __half* __restrict__ alp,
    const float* __restrict__ invS, const int* __restrict__ rowstart,
    const int* __restrict__ col, const float* __restrict__ bias,
    __half* __restrict__ h2, int N) {
    __shared__ int wsn[4][64];
    __shared__ float wal[4][64];
    const int w = threadIdx.x >> 6, lane = threadIdx.x & 63;
    const int bid = blockIdx.x;
    const int h = bid & 3;
    const int n = (bid >> 2) * 4 + w;
    if (n >= N) return;
    const int e0 = rowstart[n];
    const int deg = rowstart[n + 1] - e0;
    const int tot = deg + 1;
    const int as0 = e0 + n;
    float acc[4] = {};

    for (int base = 0; base < tot; base += 64) {
        const int cnt = min(64, tot - base);
        const int li = base + lane;
        if (li < tot) {
            wsn[w][lane] = (li < deg) ? col[e0 + li] : n;
            wal[w][lane] = (float)alp[(size_t)(as0 + li) * 4 + h];
        }
        const __half* gbase = hW + h * 256 + lane * 4;
#pragma unroll 4
        for (int i = 0; i < cnt; i++) {
            const int s2 = wsn[w][i];
            const float a = wal[w][i];
            half4 v = *reinterpret_cast<const half4*>(gbase + (size_t)s2 * 1024);
#pragma unroll
            for (int c = 0; c < 4; c++) acc[c] += a * (float)v[c];
        }
    }
    const float d = invS[n * 4 + h];
    const int cc = h * 256 + lane * 4;
    float4 bb = *(const float4*)&bias[cc];
    const float bv[4] = {bb.x, bb.y, bb.z, bb.w};
    half4 o;
#pragma unroll
    for (int c = 0; c < 4; c++) {
        float v = acc[c] * d + bv[c];
        v = v > 0.f ? v : (__expf(v) - 1.f);
        o[c] = (_Float16)v;
    }
    *reinterpret_cast<half4*>(h2 + (size_t)n * 1024 + cc) = o;
}

// ---------------------------------------------------------------- pooling (two-stage)
__global__ __launch_bounds__(128) void k_gbounds(const int* __restrict__ batch, int N,
                                                 int* __restrict__ gstart) {
    int g = threadIdx.x;
    if (g > N_GRAPHS) return;
    if (g == N_GRAPHS) { gstart[N_GRAPHS] = N; return; }
    int lo = 0, hi = N;
    while (lo < hi) {
        int mid = (lo + hi) >> 1;
        if (batch[mid] < g) lo = mid + 1; else hi = mid;
    }
    gstart[g] = lo;
}

__global__ __launch_bounds__(256) void k_pool1(const __half* __restrict__ h,
                                               const int* __restrict__ gstart,
                                               float* __restrict__ ps) {
    const int g = blockIdx.x, c = blockIdx.y, t = threadIdx.x;
    const int s = gstart[g], e = gstart[g + 1];
    const int len = e - s;
    const int cs = s + (int)(((long long)len * c) >> 3);
    const int ce = s + (int)(((long long)len * (c + 1)) >> 3);
    float sum[4] = {};
    float mx[4] = {-INFINITY, -INFINITY, -INFINITY, -INFINITY};
    for (int i = cs; i < ce; i++) {
        half4 v = *reinterpret_cast<const half4*>(h + (size_t)i * N_HC + t * 4);
#pragma unroll
        for (int k = 0; k < 4; k++) {
            float f = (float)v[k];
            sum[k] += f;
            mx[k] = fmaxf(mx[k], f);
        }
    }
    float* o = ps + ((size_t)g * 8 + c) * 2048;
    *(float4*)&o[t * 4] = make_float4(sum[0], sum[1], sum[2], sum[3]);
    *(float4*)&o[1024 + t * 4] = make_float4(mx[0], mx[1], mx[2], mx[3]);
}

__global__ __launch_bounds__(256) void k_pool2(const float* __restrict__ ps,
                                               const int* __restrict__ gstart,
                                               float* __restrict__ gout) {
    const int g = blockIdx.x, t = threadIdx.x;
    float sum[4] = {};
    float mx[4] = {-INFINITY, -INFINITY, -INFINITY, -INFINITY};
#pragma unroll
    for (int c = 0; c < 8; c++) {
        const float* o = ps + ((size_t)g * 8 + c) * 2048;
        float4 sv = *(const float4*)&o[t * 4];
        float4 mv = *(const float4*)&o[1024 + t * 4];
        sum[0] += sv.x; sum[1] += sv.y; sum[2] += sv.z; sum[3] += sv.w;
        mx[0] = fmaxf(mx[0], mv.x); mx[1] = fmaxf(mx[1], mv.y);
        mx[2] = fmaxf(mx[2], mv.z); mx[3] = fmaxf(mx[3], mv.w);
    }
    float cnt = fmaxf((float)(gstart[g + 1] - gstart[g]), 1.f);
    float inv = 1.f / cnt;
    *(float4*)(gout + (size_t)g * 2048 + t * 4) =
        make_float4(sum[0] * inv, sum[1] * inv, sum[2] * inv, sum[3] * inv);
    *(float4*)(gout + (size_t)g * 2048 + 1024 + t * 4) =
        make_float4(mx[0], mx[1], mx[2], mx[3]);
}

// ---------------------------------------------------------------- classifier
__global__ __launch_bounds__(256) void k_cls1(const float* __restrict__ g,
                                              const float* __restrict__ Wc1,
                                              const float* __restrict__ bc1,
                                              float* __restrict__ hcls) {
    __shared__ float gs[2048];
    int gb = blockIdx.x, t = threadIdx.x;
    for (int i = t; i < 2048; i += 256) gs[i] = g[(size_t)gb * 2048 + i];
    __syncthreads();
    float acc = 0.f;
    for (int k = 0; k < 2048; k++) acc += gs[k] * Wc1[(size_t)k * 256 + t];
    float v = acc + bc1[t];
    hcls[gb * 256 + t] = v > 0.f ? v : 0.f;
}

__global__ __launch_bounds__(256) void k_cls2(const float* __restrict__ hcls,
                                              const float* __restrict__ Wc2,
                                              const float* __restrict__ bc2,
                                              float* __restrict__ out) {
    int idx = blockIdx.x * 256 + threadIdx.x;
    if (idx >= N_GRAPHS * 5) return;
    int gb = idx / 5, j = idx % 5;
    float acc = 0.f;
    for (int k = 0; k < 256; k++) acc += hcls[gb * 256 + k] * Wc2[k * 5 + j];
    out[idx] = acc + bc2[j];
}

// ---------------------------------------------------------------- launch
extern "C" void kernel_launch(void* const* d_in, const int* in_sizes, int n_in,
                              void* d_out, int out_size, void* d_ws, size_t ws_size,
                              hipStream_t stream) {
    const float* x    = (const float*)d_in[0];
    const int*   ei   = (const int*)d_in[1];
    const int*   batch= (const int*)d_in[2];
    const float* Wp   = (const float*)d_in[3];
    const float* bp   = (const float*)d_in[4];
    const float* W1   = (const float*)d_in[5];
    const float* as1  = (const float*)d_in[6];
    const float* ad1  = (const float*)d_in[7];
    const float* b1   = (const float*)d_in[8];
    const float* W2   = (const float*)d_in[9];
    const float* as2  = (const float*)d_in[10];
    const float* ad2  = (const float*)d_in[11];
    const float* b2   = (const float*)d_in[12];
    const float* Wc1  = (const float*)d_in[13];
    const float* bc1  = (const float*)d_in[14];
    const float* Wc2  = (const float*)d_in[15];
    const float* bc2  = (const float*)d_in[16];
    float* out = (float*)d_out;

    const int N = in_sizes[0] / 768;   // 20000
    const int E = in_sizes[1] / 2;     // 320000
    const int MP = ((N + 127) / 128) * 128;   // 20096
    const int MB = MP / 128;                  // 157

    const int* src = ei;
    const int* dst = ei + E;

    char* ws = (char*)d_ws;
    size_t off = 0;
    auto give = [&](size_t bytes) -> void* {
        void* p = ws + off;
        off = (off + bytes + 255) & ~(size_t)255;
        return p;
    };
    __half* h0  = (__half*)give((size_t)MP * N_HID * 2);
    __half* agg1= (__half*)give((size_t)MP * N_HC * 2);
    __half* h1  = (__half*)give((size_t)MP * N_HC * 2);
    __half* hW2 = (__half*)give((size_t)MP * N_HC * 2);
    __half* h2  = (__half*)give((size_t)MP * N_HC * 2);
    __half* WpT = (__half*)give((size_t)768 * 256 * 2);
    __half* W1T = (__half*)give((size_t)256 * 1024 * 2);
    __half* W2T = (__half*)give((size_t)1024 * 1024 * 2);
    float* va   = (float*)give((size_t)8 * 256 * 4);
    float* va2  = (float*)give((size_t)8 * 1024 * 4);
    float* a_s1 = (float*)give((size_t)N * N_HEADS * 4);
    float* a_d1 = (float*)give((size_t)N * N_HEADS * 4);
    float* a_s2 = (float*)give((size_t)N * N_HEADS * 4);
    float* a_d2 = (float*)give((size_t)N * N_HEADS * 4);
    __half* alp1 = (__half*)give((size_t)(E + N) * 4 * 2);
    __half* alp2 = (__half*)give((size_t)(E + N) * 4 * 2);
    float* invS1 = (float*)give((size_t)N * 4 * 4);
    float* invS2 = (float*)give((size_t)N * 4 * 4);
    float* ps   = (float*)give((size_t)N_GRAPHS * 8 * 2048 * 4);
    int* deg     = (int*)give((size_t)N * 4);
    int* cursor  = (int*)give((size_t)N * 4);
    int* rowstart= (int*)give((size_t)(N + 1) * 4);
    int* col     = (int*)give((size_t)E * 4);
    int* gstart  = (int*)give((size_t)(N_GRAPHS + 1) * 4);
    float* gpool = (float*)give((size_t)N_GRAPHS * 2048 * 4);
    float* hcls  = (float*)give((size_t)N_GRAPHS * 256 * 4);
    (void)ws_size; (void)n_in; (void)out_size;

    // ---- CSR + prep
    hipMemsetAsync(deg, 0, (size_t)N * 4, stream);
    hipMemsetAsync(cursor, 0, (size_t)N * 4, stream);
    hipMemsetAsync(va2, 0, (size_t)8 * 1024 * 4, stream);
    k_deg<<<(E + 255) / 256, 256, 0, stream>>>(dst, E, deg);
    k_scan<<<1, 1024, 0, stream>>>(deg, rowstart, N);
    k_fill<<<(E + 255) / 256, 256, 0, stream>>>(src, dst, E, rowstart, cursor, col);
    k_gbounds<<<1, 128, 0, stream>>>(batch, N, gstart);

    k_wtt<<<dim3(256 / 32, 768 / 32), 256, 0, stream>>>(Wp, WpT, 768, 256);
    k_wtt<<<dim3(1024 / 32, 256 / 32), 256, 0, stream>>>(W1, W1T, 256, 1024);
    k_wtt<<<dim3(1024 / 32, 1024 / 32), 256, 0, stream>>>(W2, W2T, 1024, 1024);
    k_makeva<<<8, 256, 0, stream>>>(W1T, as1, ad1, va);
    k_makeva2<<<dim3(8, 8), 256, 0, stream>>>(W2T, as2, ad2, va2);

    const int NROWPAD = ((MB + 7) / 8) * 8;   // 160
    const int NGB = (N + 3) / 4;

    // ---- h0 = relu(x @ WpT + bp) fp16
    k_gemm_x<<<NROWPAD * 2, 256, 0, stream>>>(x, WpT, bp, h0, N, MB, 768, 768);

    // ---- layer 1: scores -> alpha -> gather (slice-2) -> per-head transform
    k_score8<<<NGB, 256, 0, stream>>>(h0, va, a_s1, a_d1, N);
    k_alpha<<<NGB, 256, 0, stream>>>(a_s1, a_d1, rowstart, col, alp1, invS1, N);
    k_gath1<<<NGB * 2, 256, 0, stream>>>(h0, alp1, invS1, rowstart, col, agg1, N);
    k_gemm2p<2, 0><<<dim3(2, MB, 4), 256, 0, stream>>>(
        agg1, W1T, b1, h1, N, 0, 256, 1024, 1024, 256, 65536, 256, 256);

    // ---- layer 2: scores (va2) -> alpha; W2 GEMM; gather (slice-4 head-affine)
    k_score1024<<<NGB, 256, 0, stream>>>(h1, va2, a_s2, a_d2, N);
    k_alpha<<<NGB, 256, 0, stream>>>(a_s2, a_d2, rowstart, col, alp2, invS2, N);
    k_gemm2p<0, 1><<<NROWPAD * 8, 256, 0, stream>>>(
        h1, W2T, nullptr, hW2, N, MB, 1024, 1024, 1024, 0, 0, 0, 0);
    k_gath2<<<NGB * 4, 256, 0, stream>>>(
        hW2, alp2, invS2, rowstart, col, b2, h2, N);

    // ---- pooling (two-stage) + classifier
    k_pool1<<<dim3(N_GRAPHS, 8), 256, 0, stream>>>(h2, gstart, ps);
    k_pool2<<<N_GRAPHS, 256, 0, stream>>>(ps, gstart, gpool);
    k_cls1<<<N_GRAPHS, 256, 0, stream>>>(gpool, Wc1, bc1, hcls);
    k_cls2<<<2, 256, 0, stream>>>(hcls, Wc2, bc2, out);
}

// Round 16
// 442.929 us; speedup vs baseline: 1.1274x; 1.0739x over previous
//
#include <hip/hip_runtime.h>
#include <hip/hip_fp16.h>
#include <math.h>

#define N_HID 256
#define N_HEADS 4
#define N_HC 1024
#define N_GRAPHS 64

typedef __attribute__((ext_vector_type(4))) float f32x4;
typedef _Float16 half8 __attribute__((ext_vector_type(8)));
typedef _Float16 half4 __attribute__((ext_vector_type(4)));

__device__ __forceinline__ void gl_lds16h(const __half* g, __half* l) {
    __builtin_amdgcn_global_load_lds(
        (const __attribute__((address_space(1))) unsigned int*)g,
        (__attribute__((address_space(3))) unsigned int*)l, 16, 0, 0);
}

// ---------------------------------------------------------------- CSR build
__global__ __launch_bounds__(256) void k_deg(const int* __restrict__ dst, int E,
                                             int* __restrict__ deg) {
    int e = blockIdx.x * 256 + threadIdx.x;
    if (e < E) atomicAdd(&deg[dst[e]], 1);
}

__global__ __launch_bounds__(1024) void k_scan(const int* __restrict__ deg,
                                               int* __restrict__ rowstart, int N) {
    __shared__ int part[1024];
    const int t = threadIdx.x;
    const int chunk = (N + 1023) / 1024;
    const int c0 = t * chunk;
    int s = 0;
    for (int i = 0; i < chunk; i++) {
        int idx = c0 + i;
        if (idx < N) s += deg[idx];
    }
    part[t] = s;
    __syncthreads();
    for (int off = 1; off < 1024; off <<= 1) {
        int v = (t >= off) ? part[t - off] : 0;
        __syncthreads();
        part[t] += v;
        __syncthreads();
    }
    int run = (t == 0) ? 0 : part[t - 1];
    if (t == 0) rowstart[0] = 0;
    for (int i = 0; i < chunk; i++) {
        int idx = c0 + i;
        if (idx < N) {
            run += deg[idx];
            rowstart[idx + 1] = run;
        }
    }
}

__global__ __launch_bounds__(256) void k_fill(const int* __restrict__ src,
                                              const int* __restrict__ dst, int E,
                                              const int* __restrict__ rowstart,
                                              int* __restrict__ cursor,
                                              int* __restrict__ col) {
    int e = blockIdx.x * 256 + threadIdx.x;
    if (e < E) {
        int d = dst[e];
        int p = atomicAdd(&cursor[d], 1);
        col[rowstart[d] + p] = src[e];
    }
}

// ---------------------------------------------------------------- tiled transpose fp32[K][N] -> fp16[N][K]
__global__ __launch_bounds__(256) void k_wtt(const float* __restrict__ W,
                                             __half* __restrict__ WT, int K, int N) {
    __shared__ float tile[32][33];
    const int k0 = blockIdx.y * 32, n0 = blockIdx.x * 32;
    const int tr = threadIdx.x >> 5, tc = threadIdx.x & 31;
#pragma unroll
    for (int rr = 0; rr < 4; rr++) {
        int k = k0 + tr + rr * 8;
        tile[tr + rr * 8][tc] = W[(size_t)k * N + n0 + tc];
    }
    __syncthreads();
#pragma unroll
    for (int rr = 0; rr < 4; rr++) {
        int n = n0 + tr + rr * 8;
        WT[(size_t)n * K + k0 + tc] = __float2half(tile[tc][tr + rr * 8]);
    }
}

// ---------------------------------------------------------------- va = W1_h @ att_h (layer 1, from W1T fp16)
__global__ __launch_bounds__(256) void k_makeva(const __half* __restrict__ W1T,
                                                const float* __restrict__ as1,
                                                const float* __restrict__ ad1,
                                                float* __restrict__ va) {
    __shared__ float satt[256];
    int b = blockIdx.x;       // 0..7
    int h = b & 3, isd = b >> 2;
    int k = threadIdx.x;      // 0..255
    const float* att = (isd ? ad1 : as1) + h * 256;
    satt[k] = att[k];
    __syncthreads();
    const __half* wr = W1T + (size_t)(h * 256) * 256 + k;
    float s = 0.f;
    for (int c = 0; c < 256; c++) s += __half2float(wr[(size_t)c * 256]) * satt[c];
    va[b * 256 + k] = s;
}

// ---------------------------------------------------------------- va2 = W2_h^T @ att2_h (layer 2, chunked + atomic)
__global__ __launch_bounds__(256) void k_makeva2(const __half* __restrict__ W2T,
                                                 const float* __restrict__ as2,
                                                 const float* __restrict__ ad2,
                                                 float* __restrict__ va2) {
    __shared__ float satt[32];
    int b = blockIdx.x;   // 0..7
    int h = b & 3;
    int jc = blockIdx.y;  // 0..7
    int t = threadIdx.x;
    const float* att = (b >= 4 ? ad2 : as2) + h * 256 + jc * 32;
    if (t < 32) satt[t] = att[t];
    __syncthreads();
    float s0 = 0.f, s1 = 0.f, s2 = 0.f, s3 = 0.f;
    const __half* base = W2T + (size_t)(h * 256 + jc * 32) * 1024 + t * 4;
    for (int j = 0; j < 32; j++) {
        half4 wv = *reinterpret_cast<const half4*>(base + (size_t)j * 1024);
        float a = satt[j];
        s0 += a * (float)wv[0]; s1 += a * (float)wv[1];
        s2 += a * (float)wv[2]; s3 += a * (float)wv[3];
    }
    float* o = va2 + b * 1024 + t * 4;
    atomicAdd(o + 0, s0); atomicAdd(o + 1, s1);
    atomicAdd(o + 2, s2); atomicAdd(o + 3, s3);
}

// ---------------------------------------------------------------- 2-phase dbuf fp16 MFMA GEMM (BK=32)
template <int EPI, int COSCHED>
__global__ __launch_bounds__(256) void k_gemm2p(
    const __half* __restrict__ A, const __half* __restrict__ BT,
    const float* __restrict__ bias, __half* __restrict__ C,
    int M, int NROW, int K, int lda, int ldc,
    int aoffz, int boffz, int coffz, int bofz) {
    __shared__ __half sA[2][128 * 32];
    __shared__ __half sB[2][128 * 32];
    int bm, bn;
    size_t coff = 0;
    if (COSCHED) {
        const int bid = blockIdx.x;
        const int xcd = bid & 7, j0 = bid >> 3;
        const int br = xcd + 8 * (j0 >> 3);
        const int bc = j0 & 7;
        if (br >= NROW) return;
        bm = br * 128; bn = bc * 128;
    } else {
        const int z = blockIdx.z;
        A += (size_t)z * aoffz;
        BT += (size_t)z * boffz;
        bias += z * bofz;
        coff = (size_t)z * coffz;
        bm = blockIdx.y * 128; bn = blockIdx.x * 128;
    }
    const int tid = threadIdx.x, lane = tid & 63, w = tid >> 6;
    const int wr = (w >> 1) * 64, wc = (w & 1) * 64;
    const bool isB = (w >= 2);
    const __half* gsrc = isB ? (BT + (size_t)bn * K) : (A + (size_t)bm * lda);
    const int gld = isB ? K : lda;
    const int rbase = (w & 1) * 64;
    const int lr = lane >> 2, lsl = lane & 3;
    const int g = lane >> 4, fr = lane & 15;
    const int nt = K >> 5;

    f32x4 acc[4][4] = {};

    auto STAGE = [&](int b, int t) {
        __half* sbuf = (isB ? sB[b] : sA[b]);
        const int k0 = t << 5;
#pragma unroll
        for (int c2 = 0; c2 < 4; c2++) {
            int row = rbase + c2 * 16 + lr;
            int slg = lsl ^ ((row >> 1) & 3);
            gl_lds16h(gsrc + (size_t)row * gld + k0 + slg * 8,
                      sbuf + (rbase + c2 * 16) * 32);
        }
    };

    STAGE(0, 0);
    int cur = 0;
    for (int t = 0; t < nt; ++t) {
        if (t + 1 < nt) {
            STAGE(cur ^ 1, t + 1);
            asm volatile("s_waitcnt vmcnt(4)" ::: "memory");
        } else {
            asm volatile("s_waitcnt vmcnt(0)" ::: "memory");
        }
        asm volatile("s_barrier" ::: "memory");
        half8 af[4], bf[4];
#pragma unroll
        for (int i = 0; i < 4; i++) {
            int Ra = wr + i * 16 + fr;
            af[i] = *reinterpret_cast<const half8*>(
                &sA[cur][Ra * 32 + ((g ^ ((Ra >> 1) & 3)) << 3)]);
            int Rb = wc + i * 16 + fr;
            bf[i] = *reinterpret_cast<const half8*>(
                &sB[cur][Rb * 32 + ((g ^ ((Rb >> 1) & 3)) << 3)]);
        }
#pragma unroll
        for (int i = 0; i < 4; i++)
#pragma unroll
            for (int j = 0; j < 4; j++)
                acc[i][j] = __builtin_amdgcn_mfma_f32_16x16x32_f16(af[i], bf[j], acc[i][j], 0, 0, 0);
        asm volatile("s_barrier" ::: "memory");
        cur ^= 1;
    }
    const int crow0 = (lane >> 4) * 4, ccol = lane & 15;
#pragma unroll
    for (int i = 0; i < 4; i++)
#pragma unroll
        for (int j = 0; j < 4; j++) {
            int cc = bn + wc + j * 16 + ccol;
            float bv = (EPI == 2) ? bias[cc] : 0.f;
#pragma unroll
            for (int r = 0; r < 4; r++) {
                int row = bm + wr + i * 16 + crow0 + r;
                if (row < M) {
                    float v = acc[i][j][r];
                    if (EPI == 2) { v += bv; v = v > 0.f ? v : (__expf(v) - 1.f); }
                    C[(size_t)row * ldc + coff + cc] = __float2half(v);
                }
            }
        }
}

// ---------------------------------------------------------------- fp32-A MFMA GEMM (fused convert), bias+relu
__global__ __launch_bounds__(256) void k_gemm_x(
    const float* __restrict__ A, const __half* __restrict__ BT,
    const float* __restrict__ bias, __half* __restrict__ C,
    int M, int NROW, int K, int lda) {
    __shared__ __half sA[128 * 32];
    __shared__ __half sB[128 * 32];
    const int bid = blockIdx.x;
    const int xcd = bid & 7, j0 = bid >> 3;
    const int br = xcd + 8 * (j0 >> 1);
    const int bc = j0 & 1;
    if (br >= NROW) return;
    const int bm = br * 128, bn = bc * 128;
    const int tid = threadIdx.x, lane = tid & 63, w = tid >> 6;
    const int wr = (w >> 1) * 64, wc = (w & 1) * 64;
    const int sm = tid >> 1, skb = (tid & 1) * 16;
    const bool rok = (bm + sm) < M;
    const int ph0 = (((tid & 1) * 2 + 0) ^ ((sm >> 1) & 3)) << 3;
    const int ph1 = (((tid & 1) * 2 + 1) ^ ((sm >> 1) & 3)) << 3;
    const int lr = lane >> 2, lsl = lane & 3;

    f32x4 acc[4][4] = {};

    for (int k0 = 0; k0 < K; k0 += 32) {
#pragma unroll
        for (int c = 0; c < 2; c++) {
            int rb = (w + c * 4) * 16;
            int row = rb + lr;
            int slg = lsl ^ ((row >> 1) & 3);
            gl_lds16h(BT + (size_t)(bn + row) * K + k0 + slg * 8, sB + rb * 32);
        }
        {
            const float* Arow = A + (size_t)(bm + sm) * lda + k0 + skb;
            float4 v0 = make_float4(0.f, 0.f, 0.f, 0.f), v1 = v0, v2 = v0, v3 = v0;
            if (rok) {
                v0 = *(const float4*)(Arow + 0);
                v1 = *(const float4*)(Arow + 4);
                v2 = *(const float4*)(Arow + 8);
                v3 = *(const float4*)(Arow + 12);
            }
            half8 ha, hb;
            ha[0] = (_Float16)v0.x; ha[1] = (_Float16)v0.y;
            ha[2] = (_Float16)v0.z; ha[3] = (_Float16)v0.w;
            ha[4] = (_Float16)v1.x; ha[5] = (_Float16)v1.y;
            ha[6] = (_Float16)v1.z; ha[7] = (_Float16)v1.w;
            hb[0] = (_Float16)v2.x; hb[1] = (_Float16)v2.y;
            hb[2] = (_Float16)v2.z; hb[3] = (_Float16)v2.w;
            hb[4] = (_Float16)v3.x; hb[5] = (_Float16)v3.y;
            hb[6] = (_Float16)v3.z; hb[7] = (_Float16)v3.w;
            *reinterpret_cast<half8*>(&sA[sm * 32 + ph0]) = ha;
            *reinterpret_cast<half8*>(&sA[sm * 32 + ph1]) = hb;
        }
        __syncthreads();
        half8 af[4], bf[4];
        const int g = lane >> 4, fr = lane & 15;
#pragma unroll
        for (int i = 0; i < 4; i++) {
            int Ra = wr + i * 16 + fr;
            af[i] = *reinterpret_cast<const half8*>(
                &sA[Ra * 32 + ((g ^ ((Ra >> 1) & 3)) << 3)]);
            int Rb = wc + i * 16 + fr;
            bf[i] = *reinterpret_cast<const half8*>(
                &sB[Rb * 32 + ((g ^ ((Rb >> 1) & 3)) << 3)]);
        }
#pragma unroll
        for (int i = 0; i < 4; i++)
#pragma unroll
            for (int j = 0; j < 4; j++)
                acc[i][j] = __builtin_amdgcn_mfma_f32_16x16x32_f16(af[i], bf[j], acc[i][j], 0, 0, 0);
        __syncthreads();
    }
    const int crow0 = (lane >> 4) * 4, ccol = lane & 15;
#pragma unroll
    for (int i = 0; i < 4; i++)
#pragma unroll
        for (int j = 0; j < 4; j++) {
            int cc = bn + wc + j * 16 + ccol;
            float bv = bias[cc];
#pragma unroll
            for (int r = 0; r < 4; r++) {
                int row = bm + wr + i * 16 + crow0 + r;
                if (row < M) {
                    float v = acc[i][j][r] + bv;
                    v = v > 0.f ? v : 0.f;
                    C[(size_t)row * 256 + cc] = __float2half(v);
                }
            }
        }
}

// ---------------------------------------------------------------- scores from h0 (256-wide fp16, layer 1)
__global__ __launch_bounds__(256) void k_score8(const __half* __restrict__ h0,
                                                const float* __restrict__ va,
                                                float* __restrict__ a_s,
                                                float* __restrict__ a_d, int N) {
    __shared__ float sva[8][256];
    int t = threadIdx.x;
    for (int i = t; i < 2048; i += 256) sva[i >> 8][i & 255] = va[i];
    __syncthreads();
    int wv = t >> 6, lane = t & 63;
    int n = blockIdx.x * 4 + wv;
    if (n >= N) return;
    uint2 u = *(const uint2*)(h0 + (size_t)n * 256 + lane * 4);
    __half2 q0 = __builtin_bit_cast(__half2, u.x);
    __half2 q1 = __builtin_bit_cast(__half2, u.y);
    float v0 = __half2float(q0.x), v1 = __half2float(q0.y);
    float v2 = __half2float(q1.x), v3 = __half2float(q1.y);
    float p[8];
#pragma unroll
    for (int v = 0; v < 8; v++) {
        p[v] = v0 * sva[v][lane * 4] + v1 * sva[v][lane * 4 + 1] +
               v2 * sva[v][lane * 4 + 2] + v3 * sva[v][lane * 4 + 3];
    }
#pragma unroll
    for (int off = 32; off > 0; off >>= 1)
#pragma unroll
        for (int v = 0; v < 8; v++) p[v] += __shfl_xor(p[v], off, 64);
    if (lane == 0) {
        *(float4*)&a_s[n * 4] = make_float4(p[0], p[1], p[2], p[3]);
        *(float4*)&a_d[n * 4] = make_float4(p[4], p[5], p[6], p[7]);
    }
}

// ---------------------------------------------------------------- scores from h1 via va2 (layer 2)
__global__ __launch_bounds__(256) void k_score1024(const __half* __restrict__ h1,
                                                   const float* __restrict__ va2,
                                                   float* __restrict__ a_s,
                                                   float* __restrict__ a_d, int N) {
    __shared__ float sva[8 * 1024];
    int t = threadIdx.x;
    for (int i = t; i < 8192; i += 256) sva[i] = va2[i];
    __syncthreads();
    int wv = t >> 6, lane = t & 63;
    int n = blockIdx.x * 4 + wv;
    if (n >= N) return;
    const __half* hp = h1 + (size_t)n * 1024;
    float hv[16];
#pragma unroll
    for (int seg = 0; seg < 4; seg++) {
        half4 u = *reinterpret_cast<const half4*>(hp + seg * 256 + lane * 4);
#pragma unroll
        for (int c = 0; c < 4; c++) hv[seg * 4 + c] = (float)u[c];
    }
    float p[8] = {};
#pragma unroll
    for (int v = 0; v < 8; v++) {
#pragma unroll
        for (int seg = 0; seg < 4; seg++) {
            float4 f = *(const float4*)&sva[v * 1024 + seg * 256 + lane * 4];
            p[v] += hv[seg * 4] * f.x + hv[seg * 4 + 1] * f.y +
                    hv[seg * 4 + 2] * f.z + hv[seg * 4 + 3] * f.w;
        }
    }
#pragma unroll
    for (int off = 32; off > 0; off >>= 1)
#pragma unroll
        for (int v = 0; v < 8; v++) p[v] += __shfl_xor(p[v], off, 64);
    if (lane == 0) {
        *(float4*)&a_s[n * 4] = make_float4(p[0], p[1], p[2], p[3]);
        *(float4*)&a_d[n * 4] = make_float4(p[4], p[5], p[6], p[7]);
    }
}

// ---------------------------------------------------------------- alpha precompute
__global__ __launch_bounds__(256) void k_alpha(
    const float* __restrict__ a_s, const float* __restrict__ a_d,
    const int* __restrict__ rowstart, const int* __restrict__ col,
    __half* __restrict__ alp, float* __restrict__ invS, int N) {
    const int w = threadIdx.x >> 6, lane = threadIdx.x & 63;
    const int n = blockIdx.x * 4 + w;
    if (n >= N) return;
    const int e0 = rowstart[n];
    const int deg = rowstart[n + 1] - e0;
    const int tot = deg + 1;
    const int as0 = e0 + n;
    float4 adv4 = *(const float4*)&a_d[n * 4];
    const float adv[4] = {adv4.x, adv4.y, adv4.z, adv4.w};
    float M[4] = {-INFINITY, -INFINITY, -INFINITY, -INFINITY};
    for (int base = 0; base < tot; base += 64) {
        const int li = base + lane;
        float e[4] = {-INFINITY, -INFINITY, -INFINITY, -INFINITY};
        if (li < tot) {
            const int sn = (li < deg) ? col[e0 + li] : n;
            float4 asv = *(const float4*)&a_s[sn * 4];
            const float as4[4] = {asv.x, asv.y, asv.z, asv.w};
#pragma unroll
            for (int h = 0; h < 4; h++) {
                float sc = as4[h] + adv[h];
                e[h] = sc >= 0.f ? sc : 0.2f * sc;
            }
        }
#pragma unroll
        for (int off = 32; off > 0; off >>= 1)
#pragma unroll
            for (int h = 0; h < 4; h++)
                e[h] = fmaxf(e[h], __shfl_xor(e[h], off, 64));
#pragma unroll
        for (int h = 0; h < 4; h++) M[h] = fmaxf(M[h], e[h]);
    }
    float S[4] = {0.f, 0.f, 0.f, 0.f};
    for (int base = 0; base < tot; base += 64) {
        const int li = base + lane;
        float wv[4] = {0.f, 0.f, 0.f, 0.f};
        if (li < tot) {
            const int sn = (li < deg) ? col[e0 + li] : n;
            float4 asv = *(const float4*)&a_s[sn * 4];
            const float as4[4] = {asv.x, asv.y, asv.z, asv.w};
            half4 o;
#pragma unroll
            for (int h = 0; h < 4; h++) {
                float sc = as4[h] + adv[h];
                float e = sc >= 0.f ? sc : 0.2f * sc;
                wv[h] = __expf(e - M[h]);
                o[h] = (_Float16)wv[h];
            }
            *reinterpret_cast<half4*>(alp + (size_t)(as0 + li) * 4) = o;
        }
        float sw[4] = {wv[0], wv[1], wv[2], wv[3]};
#pragma unroll
        for (int off = 32; off > 0; off >>= 1)
#pragma unroll
            for (int h = 0; h < 4; h++) sw[h] += __shfl_xor(sw[h], off, 64);
#pragma unroll
        for (int h = 0; h < 4; h++) S[h] += sw[h];
    }
    if (lane == 0) {
        *(float4*)&invS[n * 4] = make_float4(
            1.f / (S[0] + 1e-16f), 1.f / (S[1] + 1e-16f),
            1.f / (S[2] + 1e-16f), 1.f / (S[3] + 1e-16f));
    }
}

// ---------------------------------------------------------------- layer-1 gather (slice-2, no softmax)
__global__ __launch_bounds__(256) void k_gath1(
    const __half* __restrict__ h0, const __half* __restrict__ alp,
    const float* __restrict__ invS, const int* __restrict__ rowstart,
    const int* __restrict__ col, __half* __restrict__ agg1, int N) {
    __shared__ int wsn[4][64];
    __shared__ float wal[4][64][4];
    const int w = threadIdx.x >> 6, lane = threadIdx.x & 63;
    const int bid = blockIdx.x;
    const int s = bid & 1;
    const int n = (bid >> 1) * 4 + w;
    if (n >= N) return;
    const int e0 = rowstart[n];
    const int deg = rowstart[n + 1] - e0;
    const int tot = deg + 1;
    const int as0 = e0 + n;
    float acc[4][2] = {};

    for (int base = 0; base < tot; base += 64) {
        const int cnt = min(64, tot - base);
        const int li = base + lane;
        if (li < tot) {
            wsn[w][lane] = (li < deg) ? col[e0 + li] : n;
            half4 av = *reinterpret_cast<const half4*>(alp + (size_t)(as0 + li) * 4);
            *(float4*)&wal[w][lane][0] = make_float4(
                (float)av[0], (float)av[1], (float)av[2], (float)av[3]);
        }
        const __half* gbase = h0 + s * 128 + lane * 2;
#pragma unroll 2
        for (int i = 0; i < cnt; i++) {
            const int s2 = wsn[w][i];
            float4 wg = *(const float4*)&wal[w][i][0];
            const float wgt[4] = {wg.x, wg.y, wg.z, wg.w};
            __half2 hv = *(const __half2*)(gbase + (size_t)s2 * 256);
            float v0 = __half2float(hv.x), v1 = __half2float(hv.y);
#pragma unroll
            for (int h = 0; h < 4; h++) {
                acc[h][0] += wgt[h] * v0;
                acc[h][1] += wgt[h] * v1;
            }
        }
    }
    float4 dv = *(const float4*)&invS[n * 4];
    const float d[4] = {dv.x, dv.y, dv.z, dv.w};
#pragma unroll
    for (int h = 0; h < 4; h++) {
        __half2 o;
        o.x = __float2half(acc[h][0] * d[h]);
        o.y = __float2half(acc[h][1] * d[h]);
        *(__half2*)(agg1 + (size_t)n * 1024 + h * 256 + s * 128 + lane * 2) = o;
    }
}

// ---------------------------------------------------------------- layer-2 gather (slice-4 head-affine, no softmax)
__global__ __launch_bounds__(256) void k_gath2(
    const __half* __restrict__ hW, const __half* __restrict__ alp,
    const float* __restrict__ invS, const int* __restrict__ rowstart,
    const int* __restrict__ col, const float* __restrict__ bias,
    __half* __restrict__ h2, int N) {
    __shared__ int wsn[4][64];
    __shared__ float wal[4][64];
    const int w = threadIdx.x >> 6, lane = threadIdx.x & 63;
    const int bid = blockIdx.x;
    const int h = bid & 3;
    const int n = (bid >> 2) * 4 + w;
    if (n >= N) return;
    const int e0 = rowstart[n];
    const int deg = rowstart[n + 1] - e0;
    const int tot = deg + 1;
    const int as0 = e0 + n;
    float acc[4] = {};

    for (int base = 0; base < tot; base += 64) {
        const int cnt = min(64, tot - base);
        const int li = base + lane;
        if (li < tot) {
            wsn[w][lane] = (li < deg) ? col[e0 + li] : n;
            wal[w][lane] = (float)alp[(size_t)(as0 + li) * 4 + h];
        }
        const __half* gbase = hW + h * 256 + lane * 4;
#pragma unroll 4
        for (int i = 0; i < cnt; i++) {
            const int s2 = wsn[w][i];
            const float a = wal[w][i];
            half4 v = *reinterpret_cast<const half4*>(gbase + (size_t)s2 * 1024);
#pragma unroll
            for (int c = 0; c < 4; c++) acc[c] += a * (float)v[c];
        }
    }
    const float d = invS[n * 4 + h];
    const int cc = h * 256 + lane * 4;
    float4 bb = *(const float4*)&bias[cc];
    const float bv[4] = {bb.x, bb.y, bb.z, bb.w};
    half4 o;
#pragma unroll
    for (int c = 0; c < 4; c++) {
        float v = acc[c] * d + bv[c];
        v = v > 0.f ? v : (__expf(v) - 1.f);
        o[c] = (_Float16)v;
    }
    *reinterpret_cast<half4*>(h2 + (size_t)n * 1024 + cc) = o;
}

// ---------------------------------------------------------------- pooling (two-stage)
__global__ __launch_bounds__(128) void k_gbounds(const int* __restrict__ batch, int N,
                                                 int* __restrict__ gstart) {
    int g = threadIdx.x;
    if (g > N_GRAPHS) return;
    if (g == N_GRAPHS) { gstart[N_GRAPHS] = N; return; }
    int lo = 0, hi = N;
    while (lo < hi) {
        int mid = (lo + hi) >> 1;
        if (batch[mid] < g) lo = mid + 1; else hi = mid;
    }
    gstart[g] = lo;
}

__global__ __launch_bounds__(256) void k_pool1(const __half* __restrict__ h,
                                               const int* __restrict__ gstart,
                                               float* __restrict__ ps) {
    const int g = blockIdx.x, c = blockIdx.y, t = threadIdx.x;
    const int s = gstart[g], e = gstart[g + 1];
    const int len = e - s;
    const int cs = s + (int)(((long long)len * c) >> 3);
    const int ce = s + (int)(((long long)len * (c + 1)) >> 3);
    float sum[4] = {};
    float mx[4] = {-INFINITY, -INFINITY, -INFINITY, -INFINITY};
    for (int i = cs; i < ce; i++) {
        half4 v = *reinterpret_cast<const half4*>(h + (size_t)i * N_HC + t * 4);
#pragma unroll
        for (int k = 0; k < 4; k++) {
            float f = (float)v[k];
            sum[k] += f;
            mx[k] = fmaxf(mx[k], f);
        }
    }
    float* o = ps + ((size_t)g * 8 + c) * 2048;
    *(float4*)&o[t * 4] = make_float4(sum[0], sum[1], sum[2], sum[3]);
    *(float4*)&o[1024 + t * 4] = make_float4(mx[0], mx[1], mx[2], mx[3]);
}

__global__ __launch_bounds__(256) void k_pool2(const float* __restrict__ ps,
                                               const int* __restrict__ gstart,
                                               float* __restrict__ gout) {
    const int g = blockIdx.x, t = threadIdx.x;
    float sum[4] = {};
    float mx[4] = {-INFINITY, -INFINITY, -INFINITY, -INFINITY};
#pragma unroll
    for (int c = 0; c < 8; c++) {
        const float* o = ps + ((size_t)g * 8 + c) * 2048;
        float4 sv = *(const float4*)&o[t * 4];
        float4 mv = *(const float4*)&o[1024 + t * 4];
        sum[0] += sv.x; sum[1] += sv.y; sum[2] += sv.z; sum[3] += sv.w;
        mx[0] = fmaxf(mx[0], mv.x); mx[1] = fmaxf(mx[1], mv.y);
        mx[2] = fmaxf(mx[2], mv.z); mx[3] = fmaxf(mx[3], mv.w);
    }
    float cnt = fmaxf((float)(gstart[g + 1] - gstart[g]), 1.f);
    float inv = 1.f / cnt;
    *(float4*)(gout + (size_t)g * 2048 + t * 4) =
        make_float4(sum[0] * inv, sum[1] * inv, sum[2] * inv, sum[3] * inv);
    *(float4*)(gout + (size_t)g * 2048 + 1024 + t * 4) =
        make_float4(mx[0], mx[1], mx[2], mx[3]);
}

// ---------------------------------------------------------------- classifier (K-split partial GEMM)
// grid (64 graphs, 8 k-chunks), 256 thr. Partial dot over 256 K-elems,
// atomicAdd into zeroed hacc[g][t].
__global__ __launch_bounds__(256) void k_cls1p(const float* __restrict__ g,
                                               const float* __restrict__ Wc1,
                                               float* __restrict__ hacc) {
    __shared__ float gs[256];
    const int gb = blockIdx.x, kc = blockIdx.y, t = threadIdx.x;
    gs[t] = g[(size_t)gb * 2048 + kc * 256 + t];
    __syncthreads();
    float acc = 0.f;
    const float* wb = Wc1 + (size_t)(kc * 256) * 256 + t;
#pragma unroll 4
    for (int k = 0; k < 256; k++) acc += gs[k] * wb[(size_t)k * 256];
    atomicAdd(&hacc[gb * 256 + t], acc);
}

// 2 blocks x 256 thr: out[g][j] = relu(hacc[g]+bc1) . Wc2[:,j] + bc2[j]
__global__ __launch_bounds__(256) void k_cls2(const float* __restrict__ hacc,
                                              const float* __restrict__ bc1,
                                              const float* __restrict__ Wc2,
                                              const float* __restrict__ bc2,
                                              float* __restrict__ out) {
    int idx = blockIdx.x * 256 + threadIdx.x;
    if (idx >= N_GRAPHS * 5) return;
    int gb = idx / 5, j = idx % 5;
    float acc = 0.f;
    for (int k = 0; k < 256; k++) {
        float v = hacc[gb * 256 + k] + bc1[k];
        v = v > 0.f ? v : 0.f;
        acc += v * Wc2[k * 5 + j];
    }
    out[idx] = acc + bc2[j];
}

// ---------------------------------------------------------------- launch
extern "C" void kernel_launch(void* const* d_in, const int* in_sizes, int n_in,
                              void* d_out, int out_size, void* d_ws, size_t ws_size,
                              hipStream_t stream) {
    const float* x    = (const float*)d_in[0];
    const int*   ei   = (const int*)d_in[1];
    const int*   batch= (const int*)d_in[2];
    const float* Wp   = (const float*)d_in[3];
    const float* bp   = (const float*)d_in[4];
    const float* W1   = (const float*)d_in[5];
    const float* as1  = (const float*)d_in[6];
    const float* ad1  = (const float*)d_in[7];
    const float* b1   = (const float*)d_in[8];
    const float* W2   = (const float*)d_in[9];
    const float* as2  = (const float*)d_in[10];
    const float* ad2  = (const float*)d_in[11];
    const float* b2   = (const float*)d_in[12];
    const float* Wc1  = (const float*)d_in[13];
    const float* bc1  = (const float*)d_in[14];
    const float* Wc2  = (const float*)d_in[15];
    const float* bc2  = (const float*)d_in[16];
    float* out = (float*)d_out;

    const int N = in_sizes[0] / 768;   // 20000
    const int E = in_sizes[1] / 2;     // 320000
    const int MP = ((N + 127) / 128) * 128;   // 20096
    const int MB = MP / 128;                  // 157

    const int* src = ei;
    const int* dst = ei + E;

    char* ws = (char*)d_ws;
    size_t off = 0;
    auto give = [&](size_t bytes) -> void* {
        void* p = ws + off;
        off = (off + bytes + 255) & ~(size_t)255;
        return p;
    };
    __half* h0  = (__half*)give((size_t)MP * N_HID * 2);
    __half* agg1= (__half*)give((size_t)MP * N_HC * 2);
    __half* h1  = (__half*)give((size_t)MP * N_HC * 2);
    __half* hW2 = (__half*)give((size_t)MP * N_HC * 2);
    __half* h2  = (__half*)give((size_t)MP * N_HC * 2);
    __half* WpT = (__half*)give((size_t)768 * 256 * 2);
    __half* W1T = (__half*)give((size_t)256 * 1024 * 2);
    __half* W2T = (__half*)give((size_t)1024 * 1024 * 2);
    float* va   = (float*)give((size_t)8 * 256 * 4);
    float* va2  = (float*)give((size_t)8 * 1024 * 4);
    float* a_s1 = (float*)give((size_t)N * N_HEADS * 4);
    float* a_d1 = (float*)give((size_t)N * N_HEADS * 4);
    float* a_s2 = (float*)give((size_t)N * N_HEADS * 4);
    float* a_d2 = (float*)give((size_t)N * N_HEADS * 4);
    __half* alp1 = (__half*)give((size_t)(E + N) * 4 * 2);
    __half* alp2 = (__half*)give((size_t)(E + N) * 4 * 2);
    float* invS1 = (float*)give((size_t)N * 4 * 4);
    float* invS2 = (float*)give((size_t)N * 4 * 4);
    float* ps   = (float*)give((size_t)N_GRAPHS * 8 * 2048 * 4);
    int* deg     = (int*)give((size_t)N * 4);
    int* cursor  = (int*)give((size_t)N * 4);
    int* rowstart= (int*)give((size_t)(N + 1) * 4);
    int* col     = (int*)give((size_t)E * 4);
    int* gstart  = (int*)give((size_t)(N_GRAPHS + 1) * 4);
    float* gpool = (float*)give((size_t)N_GRAPHS * 2048 * 4);
    float* hacc  = (float*)give((size_t)N_GRAPHS * 256 * 4);
    (void)ws_size; (void)n_in; (void)out_size;

    // ---- CSR + prep
    hipMemsetAsync(deg, 0, (size_t)N * 4, stream);
    hipMemsetAsync(cursor, 0, (size_t)N * 4, stream);
    hipMemsetAsync(va2, 0, (size_t)8 * 1024 * 4, stream);
    hipMemsetAsync(hacc, 0, (size_t)N_GRAPHS * 256 * 4, stream);
    k_deg<<<(E + 255) / 256, 256, 0, stream>>>(dst, E, deg);
    k_scan<<<1, 1024, 0, stream>>>(deg, rowstart, N);
    k_fill<<<(E + 255) / 256, 256, 0, stream>>>(src, dst, E, rowstart, cursor, col);
    k_gbounds<<<1, 128, 0, stream>>>(batch, N, gstart);

    k_wtt<<<dim3(256 / 32, 768 / 32), 256, 0, stream>>>(Wp, WpT, 768, 256);
    k_wtt<<<dim3(1024 / 32, 256 / 32), 256, 0, stream>>>(W1, W1T, 256, 1024);
    k_wtt<<<dim3(1024 / 32, 1024 / 32), 256, 0, stream>>>(W2, W2T, 1024, 1024);
    k_makeva<<<8, 256, 0, stream>>>(W1T, as1, ad1, va);
    k_makeva2<<<dim3(8, 8), 256, 0, stream>>>(W2T, as2, ad2, va2);

    const int NROWPAD = ((MB + 7) / 8) * 8;   // 160
    const int NGB = (N + 3) / 4;

    // ---- h0 = relu(x @ WpT + bp) fp16
    k_gemm_x<<<NROWPAD * 2, 256, 0, stream>>>(x, WpT, bp, h0, N, MB, 768, 768);

    // ---- layer 1: scores -> alpha -> gather (slice-2) -> per-head transform
    k_score8<<<NGB, 256, 0, stream>>>(h0, va, a_s1, a_d1, N);
    k_alpha<<<NGB, 256, 0, stream>>>(a_s1, a_d1, rowstart, col, alp1, invS1, N);
    k_gath1<<<NGB * 2, 256, 0, stream>>>(h0, alp1, invS1, rowstart, col, agg1, N);
    k_gemm2p<2, 0><<<dim3(2, MB, 4), 256, 0, stream>>>(
        agg1, W1T, b1, h1, N, 0, 256, 1024, 1024, 256, 65536, 256, 256);

    // ---- layer 2: scores (va2) -> alpha; W2 GEMM; gather (slice-4 head-affine)
    k_score1024<<<NGB, 256, 0, stream>>>(h1, va2, a_s2, a_d2, N);
    k_alpha<<<NGB, 256, 0, stream>>>(a_s2, a_d2, rowstart, col, alp2, invS2, N);
    k_gemm2p<0, 1><<<NROWPAD * 8, 256, 0, stream>>>(
        h1, W2T, nullptr, hW2, N, MB, 1024, 1024, 1024, 0, 0, 0, 0);
    k_gath2<<<NGB * 4, 256, 0, stream>>>(
        hW2, alp2, invS2, rowstart, col, b2, h2, N);

    // ---- pooling (two-stage) + classifier (K-split)
    k_pool1<<<dim3(N_GRAPHS, 8), 256, 0, stream>>>(h2, gstart, ps);
    k_pool2<<<N_GRAPHS, 256, 0, stream>>>(ps, gstart, gpool);
    k_cls1p<<<dim3(N_GRAPHS, 8), 256, 0, stream>>>(gpool, Wc1, hacc);
    k_cls2<<<2, 256, 0, stream>>>(hacc, bc1, Wc2, bc2, out);
}